// Round 8
// baseline (733.058 us; speedup 1.0000x reference)
//
#include <hip/hip_runtime.h>
#include <hip/hip_fp16.h>

#define N_NODES 4096
#define DIMS 128

typedef __attribute__((ext_vector_type(8))) short short8;
typedef __attribute__((ext_vector_type(4))) float f32x4;

static constexpr float BIGF = 1e9f;
static constexpr float EPSF = 1e-12f;
static constexpr unsigned long long KEY_INF = ~0ull;
static constexpr unsigned U32_INF = 0xFFFFFFFFu;

// ctl layout: [0..23] per-(round,m) arrival counters, [24..25] cnt, [26..27] done, [28] sort_done
#define CTL_CNT  24
#define CTL_DONE 26
#define CTL_SORT 28

// ---------------- helpers ----------------

__device__ inline unsigned short f32_to_bf16(float f) {
    unsigned u = __float_as_uint(f);
    unsigned r = (u + 0x7FFFu + ((u >> 16) & 1u)) >> 16;   // RNE
    return (unsigned short)r;
}

__device__ inline float half_bits_to_f32(unsigned short b) {
    __half h;
    __builtin_memcpy(&h, &b, 2);
    return __half2float(h);
}

__device__ inline unsigned u32min(unsigned a, unsigned b) { return a < b ? a : b; }

__device__ inline float block_reduce_sum_256(float v) {
    __shared__ float s[4];
    __syncthreads();
    #pragma unroll
    for (int off = 32; off; off >>= 1) v += __shfl_xor(v, off);
    if ((threadIdx.x & 63) == 0) s[threadIdx.x >> 6] = v;
    __syncthreads();
    return s[0] + s[1] + s[2] + s[3];
}

// ---------------- prep: bf16 convert, norms, repr partials, init ----------------
// grid 512 x 256
__global__ __launch_bounds__(256) void prep_kernel(const float* __restrict__ S,
                                                   const float* __restrict__ T,
                                                   unsigned short* __restrict__ X16s,
                                                   unsigned short* __restrict__ X16t,
                                                   float* __restrict__ sqs,
                                                   float* __restrict__ sqt,
                                                   float* __restrict__ partials,
                                                   unsigned short* __restrict__ comp16,
                                                   unsigned long long* __restrict__ best_comp,
                                                   unsigned long long* __restrict__ best_row,
                                                   unsigned* __restrict__ ctl) {
    const int t = threadIdx.x;
    const int gid = blockIdx.x * 256 + t;
    if (gid < 2 * N_NODES) {
        comp16[gid] = (unsigned short)(gid & (N_NODES - 1));
        best_comp[gid] = KEY_INF;
        best_row[gid] = KEY_INF;
    }
    if (gid < 32) ctl[gid] = 0;

    const int wave = t >> 6, lane = t & 63;
    const int row = blockIdx.x * 8 + wave * 2 + (lane >> 5);
    const int c4 = (lane & 31) * 4;
    const size_t off = (size_t)row * DIMS + c4;
    float4 a = *(const float4*)&S[off];
    float4 b = *(const float4*)&T[off];
    float sa = a.x * a.x + a.y * a.y + a.z * a.z + a.w * a.w;
    float sb = b.x * b.x + b.y * b.y + b.z * b.z + b.w * b.w;
    #pragma unroll
    for (int m = 16; m; m >>= 1) { sa += __shfl_xor(sa, m); sb += __shfl_xor(sb, m); }
    if ((lane & 31) == 0) { sqs[row] = sa; sqt[row] = sb; }
    ushort4 oa, ob;
    oa.x = f32_to_bf16(a.x); oa.y = f32_to_bf16(a.y);
    oa.z = f32_to_bf16(a.z); oa.w = f32_to_bf16(a.w);
    ob.x = f32_to_bf16(b.x); ob.y = f32_to_bf16(b.y);
    ob.z = f32_to_bf16(b.z); ob.w = f32_to_bf16(b.w);
    *(ushort4*)&X16s[off] = oa;
    *(ushort4*)&X16t[off] = ob;
    float dx = a.x - b.x, dy = a.y - b.y, dz = a.z - b.z, dw = a.w - b.w;
    float rs = block_reduce_sum_256(dx * dx + dy * dy + dz * dz + dw * dw);
    if (t == 0) partials[blockIdx.x] = rs;
}

// ---------------- distance matrix: triangular MFMA + both-orientation write ----
// grid (64,64,2); lower-triangle blocks (bj<bi) exit. Off-diag tiles are
// computed once, written to D twice (normal + transposed via LDS tile), and
// seed best_row for BOTH the row-panel (row-min) and col-panel (col-min).
__global__ __launch_bounds__(256) void dist_kernel(const unsigned short* __restrict__ X16s,
                                                   const unsigned short* __restrict__ X16t,
                                                   const float* __restrict__ sqs,
                                                   const float* __restrict__ sqt,
                                                   __half* __restrict__ Ds,
                                                   __half* __restrict__ Dt,
                                                   unsigned long long* __restrict__ best_row) {
    const int bi = blockIdx.y * 64;
    const int bj = blockIdx.x * 64;
    if (bj < bi) return;
    const int m = blockIdx.z;
    const unsigned short* __restrict__ X16 = m ? X16t : X16s;
    const float* __restrict__ sq = m ? sqt : sqs;
    unsigned short* __restrict__ D = (unsigned short*)(m ? Dt : Ds);
    unsigned long long* br = best_row + m * N_NODES;

    __shared__ __align__(16) unsigned short Abuf[64 * 128];
    __shared__ __align__(16) unsigned short Bbuf[64 * 128];
    __shared__ unsigned colminLDS[4 * 64];
    unsigned short* tile16 = Abuf;            // aliased after barrier; 64*72*2 = 9216B

    const int t = threadIdx.x;

    #pragma unroll
    for (int p = 0; p < 4; p++) {
        int f = t + p * 256;
        int r = f >> 4, c8 = f & 15;
        int slot = c8 ^ (r & 7);
        uint4 va = *(const uint4*)&X16[(size_t)(bi + r) * DIMS + c8 * 8];
        *(uint4*)&Abuf[r * 128 + slot * 8] = va;
        uint4 vb = *(const uint4*)&X16[(size_t)(bj + r) * DIMS + c8 * 8];
        *(uint4*)&Bbuf[r * 128 + slot * 8] = vb;
    }
    __syncthreads();

    const int wave = t >> 6, lane = t & 63;
    const int l15 = lane & 15, kg = lane >> 4;

    const int rowA = wave * 16 + l15;
    short8 afrag[4];
    #pragma unroll
    for (int s = 0; s < 4; s++) {
        int c8 = s * 4 + kg;
        int slot = c8 ^ (rowA & 7);
        afrag[s] = *(const short8*)&Abuf[rowA * 128 + slot * 8];
    }
    __syncthreads();   // all Abuf reads done before tile16 aliasing writes

    f32x4 acc[4] = {};
    #pragma unroll
    for (int n = 0; n < 4; n++) {
        const int rowB = n * 16 + l15;
        #pragma unroll
        for (int s = 0; s < 4; s++) {
            int c8 = s * 4 + kg;
            int slot = c8 ^ (rowB & 7);
            short8 bfrag = *(const short8*)&Bbuf[rowB * 128 + slot * 8];
            acc[n] = __builtin_amdgcn_mfma_f32_16x16x32_bf16(afrag[s], bfrag, acc[n], 0, 0, 0);
        }
    }

    const int r0 = wave * 16 + kg * 4;
    float sqi[4];
    #pragma unroll
    for (int rr = 0; rr < 4; rr++) sqi[rr] = sq[bi + r0 + rr];

    unsigned rowmin[4] = {U32_INF, U32_INF, U32_INF, U32_INF};   // (d16<<12)|globalcol per row rr
    unsigned colmin[4] = {U32_INF, U32_INF, U32_INF, U32_INF};   // (d16<<12)|localrow per n
    #pragma unroll
    for (int n = 0; n < 4; n++) {
        const int col = bj + n * 16 + l15;
        const float sqj = sq[col];
        #pragma unroll
        for (int rr = 0; rr < 4; rr++) {
            float d2 = sqi[rr] + sqj - 2.0f * acc[n][rr];
            float dd = sqrtf(fmaxf(d2, EPSF));
            unsigned hb = (unsigned)__half_as_ushort(__float2half(dd));
            tile16[(r0 + rr) * 72 + n * 16 + l15] = (unsigned short)hb;
            if ((bi + r0 + rr) != col) {
                rowmin[rr] = u32min(rowmin[rr], (hb << 12) | (unsigned)col);
                colmin[n]  = u32min(colmin[n],  (hb << 12) | (unsigned)(r0 + rr));
            }
        }
    }
    // row-min: reduce across l15 axis (lane bits 0..3)
    #pragma unroll
    for (int rr = 0; rr < 4; rr++) {
        unsigned k = rowmin[rr];
        #pragma unroll
        for (int s = 8; s; s >>= 1) k = u32min(k, (unsigned)__shfl_xor((int)k, s));
        if (l15 == 0 && k != U32_INF) {
            const unsigned row = (unsigned)(bi + r0 + rr);
            unsigned j = k & 0xFFFu, d16 = k >> 12;
            unsigned a = row < j ? row : j, b2 = row < j ? j : row;
            atomicMin(&br[row],
                ((unsigned long long)d16 << 24) | ((unsigned long long)a << 12) | b2);
        }
    }
    // col-min: reduce across kg axis (lane bits 4..5), write per-wave slot
    #pragma unroll
    for (int n = 0; n < 4; n++) {
        unsigned k = colmin[n];
        k = u32min(k, (unsigned)__shfl_xor((int)k, 16));
        k = u32min(k, (unsigned)__shfl_xor((int)k, 32));
        if (kg == 0) colminLDS[wave * 64 + n * 16 + l15] = k;
    }
    __syncthreads();

    // normal coalesced write
    #pragma unroll
    for (int q = 0; q < 2; q++) {
        int lin = t * 2 + q;
        int r = lin >> 3, c8 = lin & 7;
        uint4 v = *(const uint4*)&tile16[r * 72 + c8 * 8];
        *(uint4*)&D[(size_t)(bi + r) * N_NODES + bj + c8 * 8] = v;
    }
    if (bi != bj) {
        // transposed write
        #pragma unroll
        for (int q = 0; q < 2; q++) {
            int lin = t * 2 + q;
            int c = lin >> 3, r8 = lin & 7;
            unsigned w[4];
            #pragma unroll
            for (int h = 0; h < 4; h++) {
                unsigned lo = tile16[(r8 * 8 + h * 2) * 72 + c];
                unsigned hi = tile16[(r8 * 8 + h * 2 + 1) * 72 + c];
                w[h] = lo | (hi << 16);
            }
            uint4 v = make_uint4(w[0], w[1], w[2], w[3]);
            *(uint4*)&D[(size_t)(bj + c) * N_NODES + bi + r8 * 8] = v;
        }
        // col-panel row-min finalize
        if (t < 64) {
            unsigned k = colminLDS[t];
            k = u32min(k, colminLDS[64 + t]);
            k = u32min(k, colminLDS[128 + t]);
            k = u32min(k, colminLDS[192 + t]);
            unsigned d16 = k >> 12, lrow = k & 0xFFFu;
            unsigned long long key64 = ((unsigned long long)d16 << 24) |
                ((unsigned long long)(bi + lrow) << 12) | (unsigned)(bj + t);
            atomicMin(&br[bj + t], key64);
        }
    }
}

// ---------------- fused Boruvka scan + last-block merge ----------------
// grid (256, 2), block 1024 (16 waves; one row per wave).
__global__ __launch_bounds__(1024) void scanmerge_kernel(const unsigned short* __restrict__ D0,
                                                         const unsigned short* __restrict__ D1,
                                                         unsigned short* __restrict__ comp16,
                                                         unsigned long long* __restrict__ best_row,
                                                         unsigned long long* __restrict__ best_comp,
                                                         float* __restrict__ deaths,
                                                         unsigned* __restrict__ ctl,
                                                         int round) {
    const int m = blockIdx.y;
    if (ctl[CTL_DONE + m]) return;
    const unsigned short* __restrict__ D = m ? D1 : D0;
    unsigned short* cm = comp16 + m * N_NODES;
    unsigned long long* br = best_row + m * N_NODES;
    unsigned long long* bc = best_comp + m * N_NODES;

    __shared__ __align__(16) unsigned short s_c16[N_NODES];   // 8 KB (scan staging)
    __shared__ unsigned short s_mc[N_NODES];                  // 8 KB (merge)
    __shared__ unsigned short s_mp[N_NODES];                  // 8 KB (merge)
    __shared__ unsigned long long s_bc[N_NODES];              // 32 KB (merge)
    __shared__ int s_need, s_last;

    const int t = threadIdx.x;
    const int wave = t >> 6, lane = t & 63;
    const int r = blockIdx.x * 16 + wave;

    if (t == 0) { s_need = 0; s_last = 0; }
    __syncthreads();

    // ---- scan phase ----
    const unsigned ci = cm[r];                    // broadcast load
    unsigned long long cached = br[r];
    bool valid;
    if (cached == KEY_INF) {
        valid = true;
    } else {
        unsigned canon = (unsigned)(cached & 0xFFFFFFu);
        unsigned a = canon >> 12, b = canon & 0xFFFu;
        unsigned j = (a == (unsigned)r) ? b : a;
        valid = (cm[j] != (unsigned short)ci);
    }
    if (!valid && lane == 0) s_need = 1;
    __syncthreads();

    if (s_need) {
        if (t < 512) {
            uint4 v = ((const uint4*)cm)[t];
            *(uint4*)&s_c16[t * 8] = v;
        }
        __syncthreads();
    }

    if (!valid) {
        unsigned best32 = U32_INF;
        const unsigned short* row = D + (size_t)r * N_NODES;
        const unsigned short ci16 = (unsigned short)ci;
        const unsigned cirep = (unsigned)ci16 | ((unsigned)ci16 << 16);
        #pragma unroll 4
        for (int it = 0; it < 8; it++) {
            const int e0 = it * 512 + lane * 8;
            uint4 dv = *(const uint4*)&row[e0];
            uint4 cv = *(const uint4*)&s_c16[e0];
            unsigned px = cv.x ^ cirep, py = cv.y ^ cirep;
            unsigned pz = cv.z ^ cirep, pw = cv.w ^ cirep;
            if (px | py | pz | pw) {
                unsigned dw4[4] = {dv.x, dv.y, dv.z, dv.w};
                unsigned pp[4] = {px, py, pz, pw};
                #pragma unroll
                for (int h = 0; h < 4; h++) {
                    unsigned j0 = (unsigned)(e0 + h * 2);
                    if (pp[h] & 0xFFFFu)
                        best32 = u32min(best32, ((dw4[h] & 0xFFFFu) << 12) | j0);
                    if (pp[h] >> 16)
                        best32 = u32min(best32, ((dw4[h] >> 16) << 12) | (j0 + 1));
                }
            }
        }
        #pragma unroll
        for (int s = 32; s; s >>= 1) best32 = u32min(best32, (unsigned)__shfl_xor((int)best32, s));
        if (best32 != U32_INF) {
            unsigned j = best32 & 0xFFFu, d16 = best32 >> 12;
            unsigned a = (unsigned)r < j ? (unsigned)r : j;
            unsigned b2 = (unsigned)r < j ? j : (unsigned)r;
            cached = ((unsigned long long)d16 << 24) | ((unsigned long long)a << 12) | b2;
        } else {
            cached = KEY_INF;
        }
        if (lane == 0) br[r] = cached;
    }
    if (lane == 0 && cached != KEY_INF) atomicMin(&bc[ci], cached);

    // ---- arrival: last block of this m runs the merge ----
    __threadfence();
    __syncthreads();
    if (t == 0) {
        unsigned old = atomicAdd(&ctl[round * 2 + m], 1u);
        if (old == gridDim.x - 1) s_last = 1;
    }
    __syncthreads();
    if (!s_last) return;
    __threadfence();

    // ---- merge phase ----
    float* dth = deaths + m * N_NODES;
    for (int i = t; i < N_NODES; i += 1024) {
        s_mc[i] = cm[i];
        s_mp[i] = (unsigned short)i;
        s_bc[i] = atomicMin(&bc[i], KEY_INF);    // coherent read (no modify)
    }
    __syncthreads();

    for (int i = t; i < N_NODES; i += 1024) {
        unsigned long long k = s_bc[i];
        if (k != KEY_INF) {
            unsigned canon = (unsigned)(k & 0xFFFFFFu);
            unsigned a = canon >> 12, b = canon & 0xFFFu;
            unsigned ca = s_mc[a], cb = s_mc[b];
            unsigned other = (ca == (unsigned)i) ? cb : ca;
            s_mp[i] = (unsigned short)other;
            bool mutual = (s_bc[other] == k);
            if (!mutual || (unsigned)i < other) {
                unsigned idx = atomicAdd(&ctl[CTL_CNT + m], 1u);
                dth[idx] = half_bits_to_f32((unsigned short)(k >> 24));
            }
        }
    }
    __syncthreads();

    unsigned nv[4];
    #pragma unroll
    for (int q = 0; q < 4; q++) {
        unsigned i = (unsigned)(t + q * 1024);
        unsigned p = s_mp[i], pp = s_mp[p];
        nv[q] = (pp == i) ? (i < p ? i : p) : p;
    }
    __syncthreads();
    #pragma unroll
    for (int q = 0; q < 4; q++) s_mp[t + q * 1024] = (unsigned short)nv[q];
    __syncthreads();

    #pragma unroll
    for (int q = 0; q < 4; q++) {
        unsigned rt = (unsigned)(t + q * 1024);
        unsigned p = s_mp[rt];
        while (p != rt) { rt = p; p = s_mp[rt]; }
        nv[q] = rt;
    }
    __syncthreads();
    #pragma unroll
    for (int q = 0; q < 4; q++) s_mp[t + q * 1024] = (unsigned short)nv[q];
    __syncthreads();

    for (int i = t; i < N_NODES; i += 1024) {
        cm[i] = s_mp[s_mc[i]];
        bc[i] = KEY_INF;
    }
    __syncthreads();
    if (t == 0) {
        unsigned c = atomicAdd(&ctl[CTL_CNT + m], 0u);
        if (c >= N_NODES - 1) ctl[CTL_DONE + m] = 1u;
    }
}

// ---------------- sort (hybrid bitonic) + last-block finalize ----------------
__global__ __launch_bounds__(1024) void sortfinal_kernel(float* __restrict__ deaths,
                                                         const float* __restrict__ partials,
                                                         unsigned* __restrict__ ctl,
                                                         float* __restrict__ out) {
    float* d = deaths + blockIdx.x * N_NODES;
    __shared__ float s[N_NODES];
    __shared__ float red[16], red2[16];
    __shared__ int s_last;
    const int t = threadIdx.x;
    if (t == 0) s_last = 0;
    for (int i = t; i < N_NODES - 1; i += 1024) s[i] = d[i];
    if (t == 0) s[N_NODES - 1] = BIGF;
    __syncthreads();

    {
        float v[4];
        #pragma unroll
        for (int q = 0; q < 4; q++) v[q] = s[t + q * 1024];
        #pragma unroll
        for (int k = 2; k <= 32; k <<= 1) {
            for (int j = k >> 1; j; j >>= 1) {
                #pragma unroll
                for (int q = 0; q < 4; q++) {
                    float o = __shfl_xor(v[q], j);
                    bool up  = (t & j) == 0;
                    bool asc = (((t + q * 1024) & k) == 0);
                    float lo = fminf(v[q], o), hi = fmaxf(v[q], o);
                    v[q] = (asc == up) ? lo : hi;
                }
            }
        }
        #pragma unroll
        for (int q = 0; q < 4; q++) s[t + q * 1024] = v[q];
    }
    __syncthreads();

    for (int k = 64; k <= N_NODES; k <<= 1) {
        for (int j = k >> 1; j >= 64; j >>= 1) {
            #pragma unroll
            for (int q = 0; q < 4; q++) {
                int i = t + q * 1024;
                int p = i ^ j;
                if (p > i) {
                    float a = s[i], b = s[p];
                    bool asc = (i & k) == 0;
                    if ((a > b) == asc) { s[i] = b; s[p] = a; }
                }
            }
            __syncthreads();
        }
        float v[4];
        #pragma unroll
        for (int q = 0; q < 4; q++) v[q] = s[t + q * 1024];
        for (int j = 32; j; j >>= 1) {
            #pragma unroll
            for (int q = 0; q < 4; q++) {
                float o = __shfl_xor(v[q], j);
                bool up  = (t & j) == 0;
                bool asc = (((t + q * 1024) & k) == 0);
                float lo = fminf(v[q], o), hi = fmaxf(v[q], o);
                v[q] = (asc == up) ? lo : hi;
            }
        }
        #pragma unroll
        for (int q = 0; q < 4; q++) s[t + q * 1024] = v[q];
        __syncthreads();
    }
    for (int i = t; i < N_NODES - 1; i += 1024) d[i] = s[i];

    // arrival
    __threadfence();
    __syncthreads();
    if (t == 0) {
        unsigned old = atomicAdd(&ctl[CTL_SORT], 1u);
        if (old == 1) s_last = 1;
    }
    __syncthreads();
    if (!s_last) return;
    __threadfence();

    // finalize: coherent reads of both sorted diagrams
    float a = 0.f;
    for (int i = t; i < N_NODES - 1; i += 1024) {
        float x = __uint_as_float(atomicAdd((unsigned*)&deaths[i], 0u));
        float y = __uint_as_float(atomicAdd((unsigned*)&deaths[N_NODES + i], 0u));
        float dd = x - y;
        a += dd * dd;
    }
    float rsum = 0.f;
    for (int i = t; i < 512; i += 1024) rsum += partials[i];
    #pragma unroll
    for (int off = 32; off; off >>= 1) { a += __shfl_xor(a, off); rsum += __shfl_xor(rsum, off); }
    if ((t & 63) == 0) { red[t >> 6] = a; red2[t >> 6] = rsum; }
    __syncthreads();
    if (t == 0) {
        float topo_sum = 0.f, repr_sum = 0.f;
        #pragma unroll
        for (int i = 0; i < 16; i++) { topo_sum += red[i]; repr_sum += red2[i]; }
        float repr = repr_sum / (float)(N_NODES * DIMS);
        float topo = topo_sum / (float)(2 * (N_NODES - 1));
        out[0] = 0.5f * repr + 0.5f * topo;
        out[1] = repr;
        out[2] = topo;
    }
}

// ---------------- host ----------------

extern "C" void kernel_launch(void* const* d_in, const int* in_sizes, int n_in,
                              void* d_out, int out_size, void* d_ws, size_t ws_size,
                              hipStream_t stream) {
    const float* S = (const float*)d_in[0];
    const float* T = (const float*)d_in[1];
    float* out = (float*)d_out;

    const size_t nn = (size_t)N_NODES * N_NODES;
    char* p = (char*)d_ws;
    __half* Ds = (__half*)p;                   p += nn * 2;
    __half* Dt = (__half*)p;                   p += nn * 2;
    unsigned short* X16s = (unsigned short*)p; p += (size_t)N_NODES * DIMS * 2;
    unsigned short* X16t = (unsigned short*)p; p += (size_t)N_NODES * DIMS * 2;
    unsigned long long* best_comp = (unsigned long long*)p; p += 2 * N_NODES * 8;
    unsigned long long* best_row  = (unsigned long long*)p; p += 2 * N_NODES * 8;
    float*    sqs      = (float*)p;    p += N_NODES * 4;
    float*    sqt      = (float*)p;    p += N_NODES * 4;
    float*    deaths   = (float*)p;    p += 2 * N_NODES * 4;
    float*    partials = (float*)p;    p += 512 * 4;
    unsigned short* comp16 = (unsigned short*)p; p += 2 * N_NODES * 2;
    unsigned* ctl      = (unsigned*)p;

    prep_kernel<<<N_NODES / 8, 256, 0, stream>>>(S, T, X16s, X16t, sqs, sqt, partials,
                                                 comp16, best_comp, best_row, ctl);

    dim3 dg(N_NODES / 64, N_NODES / 64, 2);
    dist_kernel<<<dg, 256, 0, stream>>>(X16s, X16t, sqs, sqt, Ds, Dt, best_row);

    dim3 sg(N_NODES / 16, 2);
    for (int r = 0; r < 12; r++) {
        scanmerge_kernel<<<sg, 1024, 0, stream>>>((const unsigned short*)Ds,
                                                  (const unsigned short*)Dt,
                                                  comp16, best_row, best_comp,
                                                  deaths, ctl, r);
    }
    sortfinal_kernel<<<2, 1024, 0, stream>>>(deaths, partials, ctl, out);
}

// Round 9
// 333.889 us; speedup vs baseline: 2.1955x; 2.1955x over previous
//
#include <hip/hip_runtime.h>
#include <hip/hip_fp16.h>

#define N_NODES 4096
#define DIMS 128

typedef __attribute__((ext_vector_type(8))) short short8;
typedef __attribute__((ext_vector_type(4))) float f32x4;

static constexpr float BIGF = 1e9f;
static constexpr float EPSF = 1e-12f;
static constexpr unsigned long long KEY_INF = ~0ull;
static constexpr unsigned U32_INF = 0xFFFFFFFFu;

// ---------------- helpers ----------------

__device__ inline unsigned short f32_to_bf16(float f) {
    unsigned u = __float_as_uint(f);
    unsigned r = (u + 0x7FFFu + ((u >> 16) & 1u)) >> 16;   // RNE
    return (unsigned short)r;
}

__device__ inline float half_bits_to_f32(unsigned short b) {
    __half h;
    __builtin_memcpy(&h, &b, 2);
    return __half2float(h);
}

__device__ inline unsigned u32min(unsigned a, unsigned b) { return a < b ? a : b; }

__device__ inline unsigned long long u64min(unsigned long long a, unsigned long long b) {
    return a < b ? a : b;
}

__device__ inline unsigned long long shfl_xor_u64(unsigned long long v, int m) {
    int lo = __shfl_xor((int)(unsigned)(v & 0xFFFFFFFFull), m);
    int hi = __shfl_xor((int)(unsigned)(v >> 32), m);
    return ((unsigned long long)(unsigned)hi << 32) | (unsigned)lo;
}

__device__ inline float block_reduce_sum_256(float v) {
    __shared__ float s[4];
    __syncthreads();
    #pragma unroll
    for (int off = 32; off; off >>= 1) v += __shfl_xor(v, off);
    if ((threadIdx.x & 63) == 0) s[threadIdx.x >> 6] = v;
    __syncthreads();
    return s[0] + s[1] + s[2] + s[3];
}

// ---------------- prep: bf16 convert, norms, repr partials, init ----------------
// grid 512 x 256
__global__ __launch_bounds__(256) void prep_kernel(const float* __restrict__ S,
                                                   const float* __restrict__ T,
                                                   unsigned short* __restrict__ X16s,
                                                   unsigned short* __restrict__ X16t,
                                                   float* __restrict__ sqs,
                                                   float* __restrict__ sqt,
                                                   float* __restrict__ partials,
                                                   unsigned short* __restrict__ comp16,
                                                   unsigned long long* __restrict__ best_comp,
                                                   unsigned long long* __restrict__ br4,
                                                   unsigned* __restrict__ cnt,
                                                   unsigned* __restrict__ done) {
    const int t = threadIdx.x;
    const int gid = blockIdx.x * 256 + t;
    if (gid < 2 * N_NODES) {
        comp16[gid] = (unsigned short)(gid & (N_NODES - 1));
        best_comp[gid] = KEY_INF;
        unsigned long long* b4 = br4 + (size_t)gid * 4;
        b4[0] = KEY_INF;           // dist epilogue atomicMins real edges into slot 0
        b4[1] = 0ull;              // 0 = unknown -> rescan when walk reaches it
        b4[2] = 0ull;
        b4[3] = 0ull;
    }
    if (gid < 2) { cnt[gid] = 0; done[gid] = 0; }

    const int wave = t >> 6, lane = t & 63;
    const int row = blockIdx.x * 8 + wave * 2 + (lane >> 5);
    const int c4 = (lane & 31) * 4;
    const size_t off = (size_t)row * DIMS + c4;
    float4 a = *(const float4*)&S[off];
    float4 b = *(const float4*)&T[off];
    float sa = a.x * a.x + a.y * a.y + a.z * a.z + a.w * a.w;
    float sb = b.x * b.x + b.y * b.y + b.z * b.z + b.w * b.w;
    #pragma unroll
    for (int m = 16; m; m >>= 1) { sa += __shfl_xor(sa, m); sb += __shfl_xor(sb, m); }
    if ((lane & 31) == 0) { sqs[row] = sa; sqt[row] = sb; }
    ushort4 oa, ob;
    oa.x = f32_to_bf16(a.x); oa.y = f32_to_bf16(a.y);
    oa.z = f32_to_bf16(a.z); oa.w = f32_to_bf16(a.w);
    ob.x = f32_to_bf16(b.x); ob.y = f32_to_bf16(b.y);
    ob.z = f32_to_bf16(b.z); ob.w = f32_to_bf16(b.w);
    *(ushort4*)&X16s[off] = oa;
    *(ushort4*)&X16t[off] = ob;
    float dx = a.x - b.x, dy = a.y - b.y, dz = a.z - b.z, dw = a.w - b.w;
    float rs = block_reduce_sum_256(dx * dx + dy * dy + dz * dz + dw * dw);
    if (t == 0) partials[blockIdx.x] = rs;
}

// ---------------- distance matrix: triangular MFMA + both-orientation write ----
// grid (64,64,2); lower-triangle blocks exit. Seeds br4 slot 0 for both panels.
__global__ __launch_bounds__(256) void dist_kernel(const unsigned short* __restrict__ X16s,
                                                   const unsigned short* __restrict__ X16t,
                                                   const float* __restrict__ sqs,
                                                   const float* __restrict__ sqt,
                                                   __half* __restrict__ Ds,
                                                   __half* __restrict__ Dt,
                                                   unsigned long long* __restrict__ br4) {
    const int bi = blockIdx.y * 64;
    const int bj = blockIdx.x * 64;
    if (bj < bi) return;
    const int m = blockIdx.z;
    const unsigned short* __restrict__ X16 = m ? X16t : X16s;
    const float* __restrict__ sq = m ? sqt : sqs;
    unsigned short* __restrict__ D = (unsigned short*)(m ? Dt : Ds);
    unsigned long long* br = br4 + (size_t)m * N_NODES * 4;

    __shared__ __align__(16) unsigned short Abuf[64 * 128];
    __shared__ __align__(16) unsigned short Bbuf[64 * 128];
    __shared__ unsigned colminLDS[4 * 64];
    unsigned short* tile16 = Abuf;            // aliased after barrier (64*72*2 = 9216B)

    const int t = threadIdx.x;

    #pragma unroll
    for (int p = 0; p < 4; p++) {
        int f = t + p * 256;
        int r = f >> 4, c8 = f & 15;
        int slot = c8 ^ (r & 7);
        uint4 va = *(const uint4*)&X16[(size_t)(bi + r) * DIMS + c8 * 8];
        *(uint4*)&Abuf[r * 128 + slot * 8] = va;
        uint4 vb = *(const uint4*)&X16[(size_t)(bj + r) * DIMS + c8 * 8];
        *(uint4*)&Bbuf[r * 128 + slot * 8] = vb;
    }
    __syncthreads();

    const int wave = t >> 6, lane = t & 63;
    const int l15 = lane & 15, kg = lane >> 4;

    const int rowA = wave * 16 + l15;
    short8 afrag[4];
    #pragma unroll
    for (int s = 0; s < 4; s++) {
        int c8 = s * 4 + kg;
        int slot = c8 ^ (rowA & 7);
        afrag[s] = *(const short8*)&Abuf[rowA * 128 + slot * 8];
    }
    __syncthreads();   // all Abuf reads done before tile16 aliasing writes

    f32x4 acc[4] = {};
    #pragma unroll
    for (int n = 0; n < 4; n++) {
        const int rowB = n * 16 + l15;
        #pragma unroll
        for (int s = 0; s < 4; s++) {
            int c8 = s * 4 + kg;
            int slot = c8 ^ (rowB & 7);
            short8 bfrag = *(const short8*)&Bbuf[rowB * 128 + slot * 8];
            acc[n] = __builtin_amdgcn_mfma_f32_16x16x32_bf16(afrag[s], bfrag, acc[n], 0, 0, 0);
        }
    }

    const int r0 = wave * 16 + kg * 4;
    float sqi[4];
    #pragma unroll
    for (int rr = 0; rr < 4; rr++) sqi[rr] = sq[bi + r0 + rr];

    unsigned rowmin[4] = {U32_INF, U32_INF, U32_INF, U32_INF};
    unsigned colmin[4] = {U32_INF, U32_INF, U32_INF, U32_INF};
    #pragma unroll
    for (int n = 0; n < 4; n++) {
        const int col = bj + n * 16 + l15;
        const float sqj = sq[col];
        #pragma unroll
        for (int rr = 0; rr < 4; rr++) {
            float d2 = sqi[rr] + sqj - 2.0f * acc[n][rr];
            float dd = sqrtf(fmaxf(d2, EPSF));
            unsigned hb = (unsigned)__half_as_ushort(__float2half(dd));
            tile16[(r0 + rr) * 72 + n * 16 + l15] = (unsigned short)hb;
            if ((bi + r0 + rr) != col) {
                rowmin[rr] = u32min(rowmin[rr], (hb << 12) | (unsigned)col);
                colmin[n]  = u32min(colmin[n],  (hb << 12) | (unsigned)(r0 + rr));
            }
        }
    }
    #pragma unroll
    for (int rr = 0; rr < 4; rr++) {
        unsigned k = rowmin[rr];
        #pragma unroll
        for (int s = 8; s; s >>= 1) k = u32min(k, (unsigned)__shfl_xor((int)k, s));
        if (l15 == 0 && k != U32_INF) {
            const unsigned row = (unsigned)(bi + r0 + rr);
            unsigned j = k & 0xFFFu, d16 = k >> 12;
            unsigned a = row < j ? row : j, b2 = row < j ? j : row;
            atomicMin(&br[(size_t)row * 4],
                ((unsigned long long)d16 << 24) | ((unsigned long long)a << 12) | b2);
        }
    }
    #pragma unroll
    for (int n = 0; n < 4; n++) {
        unsigned k = colmin[n];
        k = u32min(k, (unsigned)__shfl_xor((int)k, 16));
        k = u32min(k, (unsigned)__shfl_xor((int)k, 32));
        if (kg == 0) colminLDS[wave * 64 + n * 16 + l15] = k;
    }
    __syncthreads();

    #pragma unroll
    for (int q = 0; q < 2; q++) {
        int lin = t * 2 + q;
        int r = lin >> 3, c8 = lin & 7;
        uint4 v = *(const uint4*)&tile16[r * 72 + c8 * 8];
        *(uint4*)&D[(size_t)(bi + r) * N_NODES + bj + c8 * 8] = v;
    }
    if (bi != bj) {
        #pragma unroll
        for (int q = 0; q < 2; q++) {
            int lin = t * 2 + q;
            int c = lin >> 3, r8 = lin & 7;
            unsigned w[4];
            #pragma unroll
            for (int h = 0; h < 4; h++) {
                unsigned lo = tile16[(r8 * 8 + h * 2) * 72 + c];
                unsigned hi = tile16[(r8 * 8 + h * 2 + 1) * 72 + c];
                w[h] = lo | (hi << 16);
            }
            uint4 v = make_uint4(w[0], w[1], w[2], w[3]);
            *(uint4*)&D[(size_t)(bj + c) * N_NODES + bi + r8 * 8] = v;
        }
        if (t < 64) {
            unsigned k = colminLDS[t];
            k = u32min(k, colminLDS[64 + t]);
            k = u32min(k, colminLDS[128 + t]);
            k = u32min(k, colminLDS[192 + t]);
            unsigned d16 = k >> 12, lrow = k & 0xFFFu;
            unsigned long long key64 = ((unsigned long long)d16 << 24) |
                ((unsigned long long)(bi + lrow) << 12) | (unsigned)(bj + t);
            atomicMin(&br[(size_t)(bj + t) * 4], key64);
        }
    }
}

// ---------------- Boruvka scan: 4-candidate walk, rescan rebuilds list -------
// grid (256, 2), block 1024 (16 waves; one row per wave).
// br4[r][0..3]: nested minima over shrinking comp-exclusion sets. Walking the
// list, the first entry with currently-foreign endpoint is the true row min.
// Slot value 0 = unknown (rescan); KEY_INF = no foreign comps remain.
__global__ __launch_bounds__(1024) void boruvka_scan(const unsigned short* __restrict__ D0,
                                                     const unsigned short* __restrict__ D1,
                                                     const unsigned short* __restrict__ comp16,
                                                     unsigned long long* __restrict__ br4,
                                                     unsigned long long* __restrict__ best_comp,
                                                     const unsigned* __restrict__ done) {
    const int m = blockIdx.y;
    if (done[m]) return;
    const unsigned short* __restrict__ D = m ? D1 : D0;
    const unsigned short* __restrict__ cm = comp16 + m * N_NODES;
    unsigned long long* b4 = br4 + (size_t)m * N_NODES * 4;
    unsigned long long* bc = best_comp + m * N_NODES;

    __shared__ __align__(16) unsigned short s_c16[N_NODES];   // 8 KB
    __shared__ int s_need;

    const int t = threadIdx.x;
    const int wave = t >> 6, lane = t & 63;
    const int r = blockIdx.x * 16 + wave;

    if (t == 0) s_need = 0;
    __syncthreads();

    const unsigned ci = cm[r];
    unsigned long long cached = 0ull;
    bool valid = false;
    for (int i = 0; i < 4; i++) {
        unsigned long long k = b4[(size_t)r * 4 + i];
        if (k == 0ull) break;                                // unknown
        if (k == KEY_INF) { cached = KEY_INF; valid = true; break; }
        unsigned canon = (unsigned)(k & 0xFFFFFFu);
        unsigned a = canon >> 12, b = canon & 0xFFFu;
        unsigned j = (a == (unsigned)r) ? b : a;
        if (cm[j] != (unsigned short)ci) { cached = k; valid = true; break; }
    }
    if (!valid && lane == 0) s_need = 1;
    __syncthreads();

    if (s_need) {
        if (t < 512) {
            uint4 v = ((const uint4*)cm)[t];
            *(uint4*)&s_c16[t * 8] = v;
        }
        __syncthreads();
    }

    if (!valid) {
        // per-lane: up to 4 distinct-comp candidates (min key per comp,
        // replace-max eviction => holds the 4 smallest per-comp minima seen)
        unsigned ck[4] = {U32_INF, U32_INF, U32_INF, U32_INF};
        unsigned cc[4] = {0xFFFFFFu, 0xFFFFFFu, 0xFFFFFFu, 0xFFFFFFu};
        const unsigned short* row = D + (size_t)r * N_NODES;
        const unsigned ci16 = ci;
        const unsigned cirep = ci16 | (ci16 << 16);
        #pragma unroll
        for (int it = 0; it < 8; it++) {
            const int e0 = it * 512 + lane * 8;
            uint4 dv = *(const uint4*)&row[e0];
            uint4 cv = *(const uint4*)&s_c16[e0];
            unsigned dws[4] = {dv.x, dv.y, dv.z, dv.w};
            unsigned cws[4] = {cv.x, cv.y, cv.z, cv.w};
            if ((cws[0] ^ cirep) | (cws[1] ^ cirep) | (cws[2] ^ cirep) | (cws[3] ^ cirep)) {
                #pragma unroll
                for (int h = 0; h < 4; h++) {
                    #pragma unroll
                    for (int q = 0; q < 2; q++) {
                        unsigned c16 = q ? (cws[h] >> 16) : (cws[h] & 0xFFFFu);
                        if (c16 != ci16) {
                            unsigned d16 = q ? (dws[h] >> 16) : (dws[h] & 0xFFFFu);
                            unsigned key = (d16 << 12) | (unsigned)(e0 + h * 2 + q);
                            if      (c16 == cc[0]) ck[0] = u32min(ck[0], key);
                            else if (c16 == cc[1]) ck[1] = u32min(ck[1], key);
                            else if (c16 == cc[2]) ck[2] = u32min(ck[2], key);
                            else if (c16 == cc[3]) ck[3] = u32min(ck[3], key);
                            else {
                                int im = 0; unsigned mk = ck[0];
                                if (ck[1] > mk) { mk = ck[1]; im = 1; }
                                if (ck[2] > mk) { mk = ck[2]; im = 2; }
                                if (ck[3] > mk) { mk = ck[3]; im = 3; }
                                if (key < mk) { ck[im] = key; cc[im] = c16; }
                            }
                        }
                    }
                }
            }
        }
        // wave merge: 4 successive distinct-comp min-reductions
        unsigned long long out4[4];
        #pragma unroll
        for (int s = 0; s < 4; s++) {
            unsigned long long lm = KEY_INF;
            #pragma unroll
            for (int i = 0; i < 4; i++)
                if (ck[i] != U32_INF)
                    lm = u64min(lm, ((unsigned long long)ck[i] << 16) | cc[i]);
            #pragma unroll
            for (int sh = 32; sh; sh >>= 1) lm = u64min(lm, shfl_xor_u64(lm, sh));
            if (lm == KEY_INF) {
                out4[s] = KEY_INF;
            } else {
                unsigned wc = (unsigned)(lm & 0xFFFFu);
                unsigned wkey = (unsigned)(lm >> 16);
                unsigned j = wkey & 0xFFFu, d16 = wkey >> 12;
                unsigned a = (unsigned)r < j ? (unsigned)r : j;
                unsigned b2 = (unsigned)r < j ? j : (unsigned)r;
                out4[s] = ((unsigned long long)d16 << 24) |
                          ((unsigned long long)a << 12) | b2;
                #pragma unroll
                for (int i = 0; i < 4; i++) if (cc[i] == wc) ck[i] = U32_INF;
            }
        }
        if (lane == 0) {
            b4[(size_t)r * 4 + 0] = out4[0];
            b4[(size_t)r * 4 + 1] = out4[1];
            b4[(size_t)r * 4 + 2] = out4[2];
            b4[(size_t)r * 4 + 3] = out4[3];
        }
        cached = out4[0];
    }

    if (lane == 0 && cached != KEY_INF) atomicMin(&bc[ci], cached);
}

// ---------------- Boruvka merge (separate dispatch; u16 comps) ----------------
__global__ __launch_bounds__(1024) void boruvka_merge(unsigned short* __restrict__ comp16,
                                                      unsigned long long* __restrict__ best_comp,
                                                      float* __restrict__ deaths,
                                                      unsigned* __restrict__ cnt,
                                                      unsigned* __restrict__ done) {
    const int m = blockIdx.x;
    if (done[m]) return;
    unsigned short* cm = comp16 + m * N_NODES;
    unsigned long long* bc = best_comp + m * N_NODES;
    float* dth = deaths + m * N_NODES;

    __shared__ unsigned short s_mc[N_NODES];              // 8 KB
    __shared__ unsigned short s_mp[N_NODES];              // 8 KB
    __shared__ unsigned long long s_bc[N_NODES];          // 32 KB

    const int t = threadIdx.x;
    for (int i = t; i < N_NODES; i += 1024) {
        s_mc[i] = cm[i];
        s_mp[i] = (unsigned short)i;
        s_bc[i] = bc[i];
    }
    __syncthreads();

    for (int i = t; i < N_NODES; i += 1024) {
        unsigned long long k = s_bc[i];
        if (k != KEY_INF) {
            unsigned canon = (unsigned)(k & 0xFFFFFFu);
            unsigned a = canon >> 12, b = canon & 0xFFFu;
            unsigned ca = s_mc[a], cb = s_mc[b];
            unsigned other = (ca == (unsigned)i) ? cb : ca;
            s_mp[i] = (unsigned short)other;
            bool mutual = (s_bc[other] == k);
            if (!mutual || (unsigned)i < other) {
                unsigned idx = atomicAdd(&cnt[m], 1u);
                dth[idx] = half_bits_to_f32((unsigned short)(k >> 24));
            }
        }
    }
    __syncthreads();

    unsigned nv[4];
    #pragma unroll
    for (int q = 0; q < 4; q++) {
        unsigned i = (unsigned)(t + q * 1024);
        unsigned p = s_mp[i], pp = s_mp[p];
        nv[q] = (pp == i) ? (i < p ? i : p) : p;
    }
    __syncthreads();
    #pragma unroll
    for (int q = 0; q < 4; q++) s_mp[t + q * 1024] = (unsigned short)nv[q];
    __syncthreads();

    #pragma unroll
    for (int q = 0; q < 4; q++) {
        unsigned rt = (unsigned)(t + q * 1024);
        unsigned p = s_mp[rt];
        while (p != rt) { rt = p; p = s_mp[rt]; }
        nv[q] = rt;
    }
    __syncthreads();
    #pragma unroll
    for (int q = 0; q < 4; q++) s_mp[t + q * 1024] = (unsigned short)nv[q];
    __syncthreads();

    for (int i = t; i < N_NODES; i += 1024) {
        cm[i] = s_mp[s_mc[i]];
        bc[i] = KEY_INF;
    }
    __syncthreads();
    if (t == 0) {
        unsigned c = atomicAdd(&cnt[m], 0u);
        if (c >= N_NODES - 1) done[m] = 1u;
    }
}

// ---------------- sort (hybrid bitonic: shuffles for j<=32) ----------------
__global__ __launch_bounds__(1024) void sort_kernel(float* __restrict__ deaths) {
    float* d = deaths + blockIdx.x * N_NODES;
    __shared__ float s[N_NODES];
    const int t = threadIdx.x;
    for (int i = t; i < N_NODES - 1; i += 1024) s[i] = d[i];
    if (t == 0) s[N_NODES - 1] = BIGF;
    __syncthreads();

    {
        float v[4];
        #pragma unroll
        for (int q = 0; q < 4; q++) v[q] = s[t + q * 1024];
        #pragma unroll
        for (int k = 2; k <= 32; k <<= 1) {
            for (int j = k >> 1; j; j >>= 1) {
                #pragma unroll
                for (int q = 0; q < 4; q++) {
                    float o = __shfl_xor(v[q], j);
                    bool up  = (t & j) == 0;
                    bool asc = (((t + q * 1024) & k) == 0);
                    float lo = fminf(v[q], o), hi = fmaxf(v[q], o);
                    v[q] = (asc == up) ? lo : hi;
                }
            }
        }
        #pragma unroll
        for (int q = 0; q < 4; q++) s[t + q * 1024] = v[q];
    }
    __syncthreads();

    for (int k = 64; k <= N_NODES; k <<= 1) {
        for (int j = k >> 1; j >= 64; j >>= 1) {
            #pragma unroll
            for (int q = 0; q < 4; q++) {
                int i = t + q * 1024;
                int p = i ^ j;
                if (p > i) {
                    float a = s[i], b = s[p];
                    bool asc = (i & k) == 0;
                    if ((a > b) == asc) { s[i] = b; s[p] = a; }
                }
            }
            __syncthreads();
        }
        float v[4];
        #pragma unroll
        for (int q = 0; q < 4; q++) v[q] = s[t + q * 1024];
        for (int j = 32; j; j >>= 1) {
            #pragma unroll
            for (int q = 0; q < 4; q++) {
                float o = __shfl_xor(v[q], j);
                bool up  = (t & j) == 0;
                bool asc = (((t + q * 1024) & k) == 0);
                float lo = fminf(v[q], o), hi = fmaxf(v[q], o);
                v[q] = (asc == up) ? lo : hi;
            }
        }
        #pragma unroll
        for (int q = 0; q < 4; q++) s[t + q * 1024] = v[q];
        __syncthreads();
    }
    for (int i = t; i < N_NODES - 1; i += 1024) d[i] = s[i];
}

// ---------------- finalize ----------------
__global__ __launch_bounds__(256) void finalize_kernel(const float* __restrict__ deaths,
                                                       const float* __restrict__ partials,
                                                       int n_partials,
                                                       float* __restrict__ out) {
    const float* ds = deaths;
    const float* dt = deaths + N_NODES;
    float a = 0.f;
    for (int i = threadIdx.x; i < N_NODES - 1; i += 256) {
        float d = ds[i] - dt[i];
        a += d * d;
    }
    float topo_sum = block_reduce_sum_256(a);
    float r = 0.f;
    for (int i = threadIdx.x; i < n_partials; i += 256) r += partials[i];
    float repr_sum = block_reduce_sum_256(r);
    if (threadIdx.x == 0) {
        float repr = repr_sum / (float)(N_NODES * DIMS);
        float topo = topo_sum / (float)(2 * (N_NODES - 1));
        out[0] = 0.5f * repr + 0.5f * topo;
        out[1] = repr;
        out[2] = topo;
    }
}

// ---------------- host ----------------

extern "C" void kernel_launch(void* const* d_in, const int* in_sizes, int n_in,
                              void* d_out, int out_size, void* d_ws, size_t ws_size,
                              hipStream_t stream) {
    const float* S = (const float*)d_in[0];
    const float* T = (const float*)d_in[1];
    float* out = (float*)d_out;

    const size_t nn = (size_t)N_NODES * N_NODES;
    char* p = (char*)d_ws;
    __half* Ds = (__half*)p;                   p += nn * 2;
    __half* Dt = (__half*)p;                   p += nn * 2;
    unsigned short* X16s = (unsigned short*)p; p += (size_t)N_NODES * DIMS * 2;
    unsigned short* X16t = (unsigned short*)p; p += (size_t)N_NODES * DIMS * 2;
    unsigned long long* best_comp = (unsigned long long*)p; p += 2 * N_NODES * 8;
    unsigned long long* br4       = (unsigned long long*)p; p += (size_t)2 * N_NODES * 4 * 8;
    float*    sqs      = (float*)p;    p += N_NODES * 4;
    float*    sqt      = (float*)p;    p += N_NODES * 4;
    float*    deaths   = (float*)p;    p += 2 * N_NODES * 4;
    float*    partials = (float*)p;    p += 512 * 4;
    unsigned short* comp16 = (unsigned short*)p; p += 2 * N_NODES * 2;
    unsigned* cnt      = (unsigned*)p; p += 2 * 4;
    unsigned* done     = (unsigned*)p;

    prep_kernel<<<N_NODES / 8, 256, 0, stream>>>(S, T, X16s, X16t, sqs, sqt, partials,
                                                 comp16, best_comp, br4, cnt, done);

    dim3 dg(N_NODES / 64, N_NODES / 64, 2);
    dist_kernel<<<dg, 256, 0, stream>>>(X16s, X16t, sqs, sqt, Ds, Dt, br4);

    dim3 sg(N_NODES / 16, 2);
    for (int r = 0; r < 12; r++) {
        boruvka_scan<<<sg, 1024, 0, stream>>>((const unsigned short*)Ds,
                                              (const unsigned short*)Dt,
                                              comp16, br4, best_comp, done);
        boruvka_merge<<<2, 1024, 0, stream>>>(comp16, best_comp, deaths, cnt, done);
    }
    sort_kernel<<<2, 1024, 0, stream>>>(deaths);
    finalize_kernel<<<1, 256, 0, stream>>>(deaths, partials, 512, out);
}

// Round 10
// 242.722 us; speedup vs baseline: 3.0202x; 1.3756x over previous
//
#include <hip/hip_runtime.h>
#include <hip/hip_fp16.h>

#define N_NODES 4096
#define DIMS 128
#define DESCEND_CAP 16

typedef __attribute__((ext_vector_type(8))) short short8;
typedef __attribute__((ext_vector_type(4))) float f32x4;

static constexpr float BIGF = 1e9f;
static constexpr float EPSF = 1e-12f;
static constexpr unsigned long long KEY_INF = ~0ull;
static constexpr unsigned U32_INF = 0xFFFFFFFFu;

// ---------------- helpers ----------------

__device__ inline unsigned short f32_to_bf16(float f) {
    unsigned u = __float_as_uint(f);
    unsigned r = (u + 0x7FFFu + ((u >> 16) & 1u)) >> 16;   // RNE
    return (unsigned short)r;
}

__device__ inline float half_bits_to_f32(unsigned short b) {
    __half h;
    __builtin_memcpy(&h, &b, 2);
    return __half2float(h);
}

__device__ inline unsigned u32min(unsigned a, unsigned b) { return a < b ? a : b; }

__device__ inline unsigned long long u64min(unsigned long long a, unsigned long long b) {
    return a < b ? a : b;
}

__device__ inline unsigned long long shfl_xor_u64(unsigned long long v, int m) {
    int lo = __shfl_xor((int)(unsigned)(v & 0xFFFFFFFFull), m);
    int hi = __shfl_xor((int)(unsigned)(v >> 32), m);
    return ((unsigned long long)(unsigned)hi << 32) | (unsigned)lo;
}

__device__ inline float block_reduce_sum_256(float v) {
    __shared__ float s[4];
    __syncthreads();
    #pragma unroll
    for (int off = 32; off; off >>= 1) v += __shfl_xor(v, off);
    if ((threadIdx.x & 63) == 0) s[threadIdx.x >> 6] = v;
    __syncthreads();
    return s[0] + s[1] + s[2] + s[3];
}

// ---------------- prep: bf16 convert, norms, repr partials, init ----------------
// grid 512 x 256
__global__ __launch_bounds__(256) void prep_kernel(const float* __restrict__ S,
                                                   const float* __restrict__ T,
                                                   unsigned short* __restrict__ X16s,
                                                   unsigned short* __restrict__ X16t,
                                                   float* __restrict__ sqs,
                                                   float* __restrict__ sqt,
                                                   float* __restrict__ partials,
                                                   unsigned short* __restrict__ comp16,
                                                   unsigned long long* __restrict__ best_comp,
                                                   unsigned long long* __restrict__ best_row,
                                                   unsigned* __restrict__ cnt,
                                                   unsigned* __restrict__ done) {
    const int t = threadIdx.x;
    const int gid = blockIdx.x * 256 + t;
    if (gid < 2 * N_NODES) {
        comp16[gid] = (unsigned short)(gid & (N_NODES - 1));
        best_comp[gid] = KEY_INF;
        best_row[gid] = KEY_INF;               // dist epilogue atomicMins real edges in
    }
    if (gid < 2) { cnt[gid] = 0; done[gid] = 0; }

    const int wave = t >> 6, lane = t & 63;
    const int row = blockIdx.x * 8 + wave * 2 + (lane >> 5);
    const int c4 = (lane & 31) * 4;
    const size_t off = (size_t)row * DIMS + c4;
    float4 a = *(const float4*)&S[off];
    float4 b = *(const float4*)&T[off];
    float sa = a.x * a.x + a.y * a.y + a.z * a.z + a.w * a.w;
    float sb = b.x * b.x + b.y * b.y + b.z * b.z + b.w * b.w;
    #pragma unroll
    for (int m = 16; m; m >>= 1) { sa += __shfl_xor(sa, m); sb += __shfl_xor(sb, m); }
    if ((lane & 31) == 0) { sqs[row] = sa; sqt[row] = sb; }
    ushort4 oa, ob;
    oa.x = f32_to_bf16(a.x); oa.y = f32_to_bf16(a.y);
    oa.z = f32_to_bf16(a.z); oa.w = f32_to_bf16(a.w);
    ob.x = f32_to_bf16(b.x); ob.y = f32_to_bf16(b.y);
    ob.z = f32_to_bf16(b.z); ob.w = f32_to_bf16(b.w);
    *(ushort4*)&X16s[off] = oa;
    *(ushort4*)&X16t[off] = ob;
    float dx = a.x - b.x, dy = a.y - b.y, dz = a.z - b.z, dw = a.w - b.w;
    float rs = block_reduce_sum_256(dx * dx + dy * dy + dz * dz + dw * dw);
    if (t == 0) partials[blockIdx.x] = rs;
}

// ---------------- distance matrix: triangular MFMA, rowtile mins --------------
// grid (64,64,2); lower-triangle blocks exit. Writes D both orientations,
// seeds best_row (round-0 scan is free), and stores per-(row,64col-tile) min
// keys into rowtile[m][row][64] for the pruned scan (lower bounds).
__global__ __launch_bounds__(256) void dist_kernel(const unsigned short* __restrict__ X16s,
                                                   const unsigned short* __restrict__ X16t,
                                                   const float* __restrict__ sqs,
                                                   const float* __restrict__ sqt,
                                                   __half* __restrict__ Ds,
                                                   __half* __restrict__ Dt,
                                                   unsigned long long* __restrict__ best_row,
                                                   unsigned* __restrict__ rowtile) {
    const int bi = blockIdx.y * 64;
    const int bj = blockIdx.x * 64;
    if (bj < bi) return;
    const int m = blockIdx.z;
    const unsigned short* __restrict__ X16 = m ? X16t : X16s;
    const float* __restrict__ sq = m ? sqt : sqs;
    unsigned short* __restrict__ D = (unsigned short*)(m ? Dt : Ds);
    unsigned long long* br = best_row + m * N_NODES;
    unsigned* rt = rowtile + (size_t)m * N_NODES * 64;

    __shared__ __align__(16) unsigned short Abuf[64 * 128];
    __shared__ __align__(16) unsigned short Bbuf[64 * 128];
    __shared__ unsigned colminLDS[4 * 64];
    unsigned short* tile16 = Abuf;            // aliased after barrier (64*72*2 = 9216B)

    const int t = threadIdx.x;

    #pragma unroll
    for (int p = 0; p < 4; p++) {
        int f = t + p * 256;
        int r = f >> 4, c8 = f & 15;
        int slot = c8 ^ (r & 7);
        uint4 va = *(const uint4*)&X16[(size_t)(bi + r) * DIMS + c8 * 8];
        *(uint4*)&Abuf[r * 128 + slot * 8] = va;
        uint4 vb = *(const uint4*)&X16[(size_t)(bj + r) * DIMS + c8 * 8];
        *(uint4*)&Bbuf[r * 128 + slot * 8] = vb;
    }
    __syncthreads();

    const int wave = t >> 6, lane = t & 63;
    const int l15 = lane & 15, kg = lane >> 4;

    const int rowA = wave * 16 + l15;
    short8 afrag[4];
    #pragma unroll
    for (int s = 0; s < 4; s++) {
        int c8 = s * 4 + kg;
        int slot = c8 ^ (rowA & 7);
        afrag[s] = *(const short8*)&Abuf[rowA * 128 + slot * 8];
    }
    __syncthreads();   // all Abuf reads done before tile16 aliasing writes

    f32x4 acc[4] = {};
    #pragma unroll
    for (int n = 0; n < 4; n++) {
        const int rowB = n * 16 + l15;
        #pragma unroll
        for (int s = 0; s < 4; s++) {
            int c8 = s * 4 + kg;
            int slot = c8 ^ (rowB & 7);
            short8 bfrag = *(const short8*)&Bbuf[rowB * 128 + slot * 8];
            acc[n] = __builtin_amdgcn_mfma_f32_16x16x32_bf16(afrag[s], bfrag, acc[n], 0, 0, 0);
        }
    }

    const int r0 = wave * 16 + kg * 4;
    float sqi[4];
    #pragma unroll
    for (int rr = 0; rr < 4; rr++) sqi[rr] = sq[bi + r0 + rr];

    unsigned rowmin[4] = {U32_INF, U32_INF, U32_INF, U32_INF};   // (d16<<12)|globalcol
    unsigned colmin[4] = {U32_INF, U32_INF, U32_INF, U32_INF};   // (d16<<12)|localrow
    #pragma unroll
    for (int n = 0; n < 4; n++) {
        const int col = bj + n * 16 + l15;
        const float sqj = sq[col];
        #pragma unroll
        for (int rr = 0; rr < 4; rr++) {
            float d2 = sqi[rr] + sqj - 2.0f * acc[n][rr];
            float dd = sqrtf(fmaxf(d2, EPSF));
            unsigned hb = (unsigned)__half_as_ushort(__float2half(dd));
            tile16[(r0 + rr) * 72 + n * 16 + l15] = (unsigned short)hb;
            if ((bi + r0 + rr) != col) {
                rowmin[rr] = u32min(rowmin[rr], (hb << 12) | (unsigned)col);
                colmin[n]  = u32min(colmin[n],  (hb << 12) | (unsigned)(r0 + rr));
            }
        }
    }
    #pragma unroll
    for (int rr = 0; rr < 4; rr++) {
        unsigned k = rowmin[rr];
        #pragma unroll
        for (int s = 8; s; s >>= 1) k = u32min(k, (unsigned)__shfl_xor((int)k, s));
        if (l15 == 0) {
            const unsigned row = (unsigned)(bi + r0 + rr);
            rt[(size_t)row * 64 + (bj >> 6)] = k;            // tile lower bound
            unsigned j = k & 0xFFFu, d16 = k >> 12;
            unsigned a = row < j ? row : j, b2 = row < j ? j : row;
            atomicMin(&br[row],
                ((unsigned long long)d16 << 24) | ((unsigned long long)a << 12) | b2);
        }
    }
    #pragma unroll
    for (int n = 0; n < 4; n++) {
        unsigned k = colmin[n];
        k = u32min(k, (unsigned)__shfl_xor((int)k, 16));
        k = u32min(k, (unsigned)__shfl_xor((int)k, 32));
        if (kg == 0) colminLDS[wave * 64 + n * 16 + l15] = k;
    }
    __syncthreads();

    #pragma unroll
    for (int q = 0; q < 2; q++) {
        int lin = t * 2 + q;
        int r = lin >> 3, c8 = lin & 7;
        uint4 v = *(const uint4*)&tile16[r * 72 + c8 * 8];
        *(uint4*)&D[(size_t)(bi + r) * N_NODES + bj + c8 * 8] = v;
    }
    if (bi != bj) {
        #pragma unroll
        for (int q = 0; q < 2; q++) {
            int lin = t * 2 + q;
            int c = lin >> 3, r8 = lin & 7;
            unsigned w[4];
            #pragma unroll
            for (int h = 0; h < 4; h++) {
                unsigned lo = tile16[(r8 * 8 + h * 2) * 72 + c];
                unsigned hi = tile16[(r8 * 8 + h * 2 + 1) * 72 + c];
                w[h] = lo | (hi << 16);
            }
            uint4 v = make_uint4(w[0], w[1], w[2], w[3]);
            *(uint4*)&D[(size_t)(bj + c) * N_NODES + bi + r8 * 8] = v;
        }
        if (t < 64) {
            unsigned k = colminLDS[t];
            k = u32min(k, colminLDS[64 + t]);
            k = u32min(k, colminLDS[128 + t]);
            k = u32min(k, colminLDS[192 + t]);
            unsigned d16 = k >> 12, lrow = k & 0xFFFu;
            rt[(size_t)(bj + t) * 64 + (bi >> 6)] = (d16 << 12) | (unsigned)(bi + lrow);
            unsigned long long key64 = ((unsigned long long)d16 << 24) |
                ((unsigned long long)(bi + lrow) << 12) | (unsigned)(bj + t);
            atomicMin(&br[bj + t], key64);
        }
    }
}

// ---------------- Boruvka scan: cached edge -> tile-pruned -> linear fallback -
// grid (256, 2), block 1024 (16 independent waves; one row per wave; no LDS).
__global__ __launch_bounds__(1024) void boruvka_scan(const unsigned short* __restrict__ D0,
                                                     const unsigned short* __restrict__ D1,
                                                     const unsigned short* __restrict__ comp16,
                                                     const unsigned* __restrict__ rowtile,
                                                     unsigned long long* __restrict__ best_row,
                                                     unsigned long long* __restrict__ best_comp,
                                                     const unsigned* __restrict__ done) {
    const int m = blockIdx.y;
    if (done[m]) return;
    const unsigned short* __restrict__ D = m ? D1 : D0;
    const unsigned short* __restrict__ cm = comp16 + m * N_NODES;
    const unsigned* __restrict__ rt = rowtile + (size_t)m * N_NODES * 64;
    unsigned long long* br = best_row + m * N_NODES;
    unsigned long long* bc = best_comp + m * N_NODES;

    const int t = threadIdx.x;
    const int wave = t >> 6, lane = t & 63;
    const int r = blockIdx.x * 16 + wave;

    const unsigned short ci16 = cm[r];
    unsigned long long cached = br[r];
    bool valid;
    if (cached == KEY_INF) {
        valid = true;                          // no foreign comps remain
    } else {
        unsigned canon = (unsigned)(cached & 0xFFFFFFu);
        unsigned a = canon >> 12, b = canon & 0xFFFu;
        unsigned j = (a == (unsigned)r) ? b : a;
        valid = (cm[j] != ci16);
    }

    if (!valid) {
        const unsigned short* row = D + (size_t)r * N_NODES;
        // --- tile-pruned branch & bound ---
        unsigned tm = rt[(size_t)r * 64 + lane];   // lane <-> tile
        bool scanned = false;
        unsigned B = U32_INF;                       // best foreign (d16<<12)|col
        #pragma unroll 1
        for (int it = 0; it < DESCEND_CAP; it++) {
            unsigned long long my = ((unsigned long long)(scanned ? U32_INF : tm) << 8) | (unsigned)lane;
            #pragma unroll
            for (int s = 32; s; s >>= 1) my = u64min(my, shfl_xor_u64(my, s));
            unsigned wtm = (unsigned)(my >> 8);
            if (wtm >= B) break;                    // no tile can beat current best
            int tl = (int)(my & 0xFFu);
            int c0 = tl * 64 + lane;
            unsigned short dv = row[c0];
            unsigned short cv = cm[c0];
            unsigned cand = (cv != ci16) ? (((unsigned)dv << 12) | (unsigned)c0) : U32_INF;
            #pragma unroll
            for (int s = 32; s; s >>= 1) cand = u32min(cand, (unsigned)__shfl_xor((int)cand, s));
            B = u32min(B, cand);
            if (lane == tl) scanned = true;
        }
        // fallback needed if an unscanned tile could still beat B
        {
            unsigned myr = scanned ? U32_INF : tm;
            #pragma unroll
            for (int s = 32; s; s >>= 1) myr = u32min(myr, (unsigned)__shfl_xor((int)myr, s));
            if (myr < B) {
                // linear full-row scan (comps from global, L2-hot)
                unsigned best32 = B;
                const unsigned cirep = (unsigned)ci16 | ((unsigned)ci16 << 16);
                #pragma unroll 4
                for (int it = 0; it < 8; it++) {
                    const int e0 = it * 512 + lane * 8;
                    uint4 dvv = *(const uint4*)&row[e0];
                    uint4 cvv = *(const uint4*)&cm[e0];
                    unsigned px = cvv.x ^ cirep, py = cvv.y ^ cirep;
                    unsigned pz = cvv.z ^ cirep, pw = cvv.w ^ cirep;
                    if (px | py | pz | pw) {
                        unsigned dws[4] = {dvv.x, dvv.y, dvv.z, dvv.w};
                        unsigned pp[4] = {px, py, pz, pw};
                        #pragma unroll
                        for (int h = 0; h < 4; h++) {
                            unsigned j0 = (unsigned)(e0 + h * 2);
                            if (pp[h] & 0xFFFFu)
                                best32 = u32min(best32, ((dws[h] & 0xFFFFu) << 12) | j0);
                            if (pp[h] >> 16)
                                best32 = u32min(best32, ((dws[h] >> 16) << 12) | (j0 + 1));
                        }
                    }
                }
                #pragma unroll
                for (int s = 32; s; s >>= 1) best32 = u32min(best32, (unsigned)__shfl_xor((int)best32, s));
                B = best32;
            }
        }
        if (B != U32_INF) {
            unsigned j = B & 0xFFFu, d16 = B >> 12;
            unsigned a = (unsigned)r < j ? (unsigned)r : j;
            unsigned b2 = (unsigned)r < j ? j : (unsigned)r;
            cached = ((unsigned long long)d16 << 24) | ((unsigned long long)a << 12) | b2;
        } else {
            cached = KEY_INF;
        }
        if (lane == 0) br[r] = cached;
    }

    if (lane == 0 && cached != KEY_INF) atomicMin(&bc[ci16], cached);
}

// ---------------- Boruvka merge (separate dispatch; u16 comps) ----------------
__global__ __launch_bounds__(1024) void boruvka_merge(unsigned short* __restrict__ comp16,
                                                      unsigned long long* __restrict__ best_comp,
                                                      float* __restrict__ deaths,
                                                      unsigned* __restrict__ cnt,
                                                      unsigned* __restrict__ done) {
    const int m = blockIdx.x;
    if (done[m]) return;
    unsigned short* cm = comp16 + m * N_NODES;
    unsigned long long* bc = best_comp + m * N_NODES;
    float* dth = deaths + m * N_NODES;

    __shared__ unsigned short s_mc[N_NODES];
    __shared__ unsigned short s_mp[N_NODES];
    __shared__ unsigned long long s_bc[N_NODES];

    const int t = threadIdx.x;
    for (int i = t; i < N_NODES; i += 1024) {
        s_mc[i] = cm[i];
        s_mp[i] = (unsigned short)i;
        s_bc[i] = bc[i];
    }
    __syncthreads();

    for (int i = t; i < N_NODES; i += 1024) {
        unsigned long long k = s_bc[i];
        if (k != KEY_INF) {
            unsigned canon = (unsigned)(k & 0xFFFFFFu);
            unsigned a = canon >> 12, b = canon & 0xFFFu;
            unsigned ca = s_mc[a], cb = s_mc[b];
            unsigned other = (ca == (unsigned)i) ? cb : ca;
            s_mp[i] = (unsigned short)other;
            bool mutual = (s_bc[other] == k);
            if (!mutual || (unsigned)i < other) {
                unsigned idx = atomicAdd(&cnt[m], 1u);
                dth[idx] = half_bits_to_f32((unsigned short)(k >> 24));
            }
        }
    }
    __syncthreads();

    unsigned nv[4];
    #pragma unroll
    for (int q = 0; q < 4; q++) {
        unsigned i = (unsigned)(t + q * 1024);
        unsigned p = s_mp[i], pp = s_mp[p];
        nv[q] = (pp == i) ? (i < p ? i : p) : p;
    }
    __syncthreads();
    #pragma unroll
    for (int q = 0; q < 4; q++) s_mp[t + q * 1024] = (unsigned short)nv[q];
    __syncthreads();

    #pragma unroll
    for (int q = 0; q < 4; q++) {
        unsigned rt = (unsigned)(t + q * 1024);
        unsigned p = s_mp[rt];
        while (p != rt) { rt = p; p = s_mp[rt]; }
        nv[q] = rt;
    }
    __syncthreads();
    #pragma unroll
    for (int q = 0; q < 4; q++) s_mp[t + q * 1024] = (unsigned short)nv[q];
    __syncthreads();

    for (int i = t; i < N_NODES; i += 1024) {
        cm[i] = s_mp[s_mc[i]];
        bc[i] = KEY_INF;
    }
    __syncthreads();
    if (t == 0) {
        unsigned c = atomicAdd(&cnt[m], 0u);
        if (c >= N_NODES - 1) done[m] = 1u;
    }
}

// ---------------- sort (hybrid bitonic: shuffles for j<=32) ----------------
__global__ __launch_bounds__(1024) void sort_kernel(float* __restrict__ deaths) {
    float* d = deaths + blockIdx.x * N_NODES;
    __shared__ float s[N_NODES];
    const int t = threadIdx.x;
    for (int i = t; i < N_NODES - 1; i += 1024) s[i] = d[i];
    if (t == 0) s[N_NODES - 1] = BIGF;
    __syncthreads();

    {
        float v[4];
        #pragma unroll
        for (int q = 0; q < 4; q++) v[q] = s[t + q * 1024];
        #pragma unroll
        for (int k = 2; k <= 32; k <<= 1) {
            for (int j = k >> 1; j; j >>= 1) {
                #pragma unroll
                for (int q = 0; q < 4; q++) {
                    float o = __shfl_xor(v[q], j);
                    bool up  = (t & j) == 0;
                    bool asc = (((t + q * 1024) & k) == 0);
                    float lo = fminf(v[q], o), hi = fmaxf(v[q], o);
                    v[q] = (asc == up) ? lo : hi;
                }
            }
        }
        #pragma unroll
        for (int q = 0; q < 4; q++) s[t + q * 1024] = v[q];
    }
    __syncthreads();

    for (int k = 64; k <= N_NODES; k <<= 1) {
        for (int j = k >> 1; j >= 64; j >>= 1) {
            #pragma unroll
            for (int q = 0; q < 4; q++) {
                int i = t + q * 1024;
                int p = i ^ j;
                if (p > i) {
                    float a = s[i], b = s[p];
                    bool asc = (i & k) == 0;
                    if ((a > b) == asc) { s[i] = b; s[p] = a; }
                }
            }
            __syncthreads();
        }
        float v[4];
        #pragma unroll
        for (int q = 0; q < 4; q++) v[q] = s[t + q * 1024];
        for (int j = 32; j; j >>= 1) {
            #pragma unroll
            for (int q = 0; q < 4; q++) {
                float o = __shfl_xor(v[q], j);
                bool up  = (t & j) == 0;
                bool asc = (((t + q * 1024) & k) == 0);
                float lo = fminf(v[q], o), hi = fmaxf(v[q], o);
                v[q] = (asc == up) ? lo : hi;
            }
        }
        #pragma unroll
        for (int q = 0; q < 4; q++) s[t + q * 1024] = v[q];
        __syncthreads();
    }
    for (int i = t; i < N_NODES - 1; i += 1024) d[i] = s[i];
}

// ---------------- finalize ----------------
__global__ __launch_bounds__(256) void finalize_kernel(const float* __restrict__ deaths,
                                                       const float* __restrict__ partials,
                                                       int n_partials,
                                                       float* __restrict__ out) {
    const float* ds = deaths;
    const float* dt = deaths + N_NODES;
    float a = 0.f;
    for (int i = threadIdx.x; i < N_NODES - 1; i += 256) {
        float d = ds[i] - dt[i];
        a += d * d;
    }
    float topo_sum = block_reduce_sum_256(a);
    float r = 0.f;
    for (int i = threadIdx.x; i < n_partials; i += 256) r += partials[i];
    float repr_sum = block_reduce_sum_256(r);
    if (threadIdx.x == 0) {
        float repr = repr_sum / (float)(N_NODES * DIMS);
        float topo = topo_sum / (float)(2 * (N_NODES - 1));
        out[0] = 0.5f * repr + 0.5f * topo;
        out[1] = repr;
        out[2] = topo;
    }
}

// ---------------- host ----------------

extern "C" void kernel_launch(void* const* d_in, const int* in_sizes, int n_in,
                              void* d_out, int out_size, void* d_ws, size_t ws_size,
                              hipStream_t stream) {
    const float* S = (const float*)d_in[0];
    const float* T = (const float*)d_in[1];
    float* out = (float*)d_out;

    const size_t nn = (size_t)N_NODES * N_NODES;
    char* p = (char*)d_ws;
    __half* Ds = (__half*)p;                   p += nn * 2;
    __half* Dt = (__half*)p;                   p += nn * 2;
    unsigned short* X16s = (unsigned short*)p; p += (size_t)N_NODES * DIMS * 2;
    unsigned short* X16t = (unsigned short*)p; p += (size_t)N_NODES * DIMS * 2;
    unsigned long long* best_comp = (unsigned long long*)p; p += 2 * N_NODES * 8;
    unsigned long long* best_row  = (unsigned long long*)p; p += 2 * N_NODES * 8;
    unsigned* rowtile  = (unsigned*)p; p += (size_t)2 * N_NODES * 64 * 4;
    float*    sqs      = (float*)p;    p += N_NODES * 4;
    float*    sqt      = (float*)p;    p += N_NODES * 4;
    float*    deaths   = (float*)p;    p += 2 * N_NODES * 4;
    float*    partials = (float*)p;    p += 512 * 4;
    unsigned short* comp16 = (unsigned short*)p; p += 2 * N_NODES * 2;
    unsigned* cnt      = (unsigned*)p; p += 2 * 4;
    unsigned* done     = (unsigned*)p;

    prep_kernel<<<N_NODES / 8, 256, 0, stream>>>(S, T, X16s, X16t, sqs, sqt, partials,
                                                 comp16, best_comp, best_row, cnt, done);

    dim3 dg(N_NODES / 64, N_NODES / 64, 2);
    dist_kernel<<<dg, 256, 0, stream>>>(X16s, X16t, sqs, sqt, Ds, Dt, best_row, rowtile);

    dim3 sg(N_NODES / 16, 2);
    for (int r = 0; r < 12; r++) {
        boruvka_scan<<<sg, 1024, 0, stream>>>((const unsigned short*)Ds,
                                              (const unsigned short*)Dt,
                                              comp16, rowtile, best_row, best_comp, done);
        boruvka_merge<<<2, 1024, 0, stream>>>(comp16, best_comp, deaths, cnt, done);
    }
    sort_kernel<<<2, 1024, 0, stream>>>(deaths);
    finalize_kernel<<<1, 256, 0, stream>>>(deaths, partials, 512, out);
}

// Round 11
// 240.242 us; speedup vs baseline: 3.0513x; 1.0103x over previous
//
#include <hip/hip_runtime.h>
#include <hip/hip_fp16.h>

#define N_NODES 4096
#define DIMS 128
#define DESCEND_CAP 16

typedef __attribute__((ext_vector_type(8))) short short8;
typedef __attribute__((ext_vector_type(4))) float f32x4;

static constexpr float BIGF = 1e9f;
static constexpr float EPSF = 1e-12f;
static constexpr unsigned long long KEY_INF = ~0ull;
static constexpr unsigned U32_INF = 0xFFFFFFFFu;

// ---------------- helpers ----------------

__device__ inline unsigned short f32_to_bf16(float f) {
    unsigned u = __float_as_uint(f);
    unsigned r = (u + 0x7FFFu + ((u >> 16) & 1u)) >> 16;   // RNE
    return (unsigned short)r;
}

__device__ inline float half_bits_to_f32(unsigned short b) {
    __half h;
    __builtin_memcpy(&h, &b, 2);
    return __half2float(h);
}

__device__ inline unsigned u32min(unsigned a, unsigned b) { return a < b ? a : b; }

__device__ inline unsigned long long u64min(unsigned long long a, unsigned long long b) {
    return a < b ? a : b;
}

__device__ inline unsigned long long shfl_xor_u64(unsigned long long v, int m) {
    int lo = __shfl_xor((int)(unsigned)(v & 0xFFFFFFFFull), m);
    int hi = __shfl_xor((int)(unsigned)(v >> 32), m);
    return ((unsigned long long)(unsigned)hi << 32) | (unsigned)lo;
}

__device__ inline float block_reduce_sum_256(float v) {
    __shared__ float s[4];
    __syncthreads();
    #pragma unroll
    for (int off = 32; off; off >>= 1) v += __shfl_xor(v, off);
    if ((threadIdx.x & 63) == 0) s[threadIdx.x >> 6] = v;
    __syncthreads();
    return s[0] + s[1] + s[2] + s[3];
}

// ---------------- prep: bf16 convert, norms, repr partials, init ----------------
// grid 512 x 256
__global__ __launch_bounds__(256) void prep_kernel(const float* __restrict__ S,
                                                   const float* __restrict__ T,
                                                   unsigned short* __restrict__ X16s,
                                                   unsigned short* __restrict__ X16t,
                                                   float* __restrict__ sqs,
                                                   float* __restrict__ sqt,
                                                   float* __restrict__ partials,
                                                   unsigned short* __restrict__ comp16,
                                                   unsigned long long* __restrict__ best_comp,
                                                   unsigned long long* __restrict__ best_row,
                                                   unsigned* __restrict__ cnt,
                                                   unsigned* __restrict__ done) {
    const int t = threadIdx.x;
    const int gid = blockIdx.x * 256 + t;
    if (gid < 2 * N_NODES) {
        comp16[gid] = (unsigned short)(gid & (N_NODES - 1));
        best_comp[gid] = KEY_INF;
        best_row[gid] = KEY_INF;               // dist epilogue atomicMins real edges in
    }
    if (gid < 2) { cnt[gid] = 0; done[gid] = 0; }

    const int wave = t >> 6, lane = t & 63;
    const int row = blockIdx.x * 8 + wave * 2 + (lane >> 5);
    const int c4 = (lane & 31) * 4;
    const size_t off = (size_t)row * DIMS + c4;
    float4 a = *(const float4*)&S[off];
    float4 b = *(const float4*)&T[off];
    float sa = a.x * a.x + a.y * a.y + a.z * a.z + a.w * a.w;
    float sb = b.x * b.x + b.y * b.y + b.z * b.z + b.w * b.w;
    #pragma unroll
    for (int m = 16; m; m >>= 1) { sa += __shfl_xor(sa, m); sb += __shfl_xor(sb, m); }
    if ((lane & 31) == 0) { sqs[row] = sa; sqt[row] = sb; }
    ushort4 oa, ob;
    oa.x = f32_to_bf16(a.x); oa.y = f32_to_bf16(a.y);
    oa.z = f32_to_bf16(a.z); oa.w = f32_to_bf16(a.w);
    ob.x = f32_to_bf16(b.x); ob.y = f32_to_bf16(b.y);
    ob.z = f32_to_bf16(b.z); ob.w = f32_to_bf16(b.w);
    *(ushort4*)&X16s[off] = oa;
    *(ushort4*)&X16t[off] = ob;
    float dx = a.x - b.x, dy = a.y - b.y, dz = a.z - b.z, dw = a.w - b.w;
    float rs = block_reduce_sum_256(dx * dx + dy * dy + dz * dz + dw * dw);
    if (t == 0) partials[blockIdx.x] = rs;
}

// ---------------- distance matrix: triangular MFMA, rowtile mins --------------
// grid (64,64,2); lower-triangle blocks exit. Writes D both orientations,
// seeds best_row (round-0 scan is free), and stores per-(row,64col-tile) min
// keys into rowtile[m][row][64] for the pruned scan (lower bounds).
__global__ __launch_bounds__(256) void dist_kernel(const unsigned short* __restrict__ X16s,
                                                   const unsigned short* __restrict__ X16t,
                                                   const float* __restrict__ sqs,
                                                   const float* __restrict__ sqt,
                                                   __half* __restrict__ Ds,
                                                   __half* __restrict__ Dt,
                                                   unsigned long long* __restrict__ best_row,
                                                   unsigned* __restrict__ rowtile) {
    const int bi = blockIdx.y * 64;
    const int bj = blockIdx.x * 64;
    if (bj < bi) return;
    const int m = blockIdx.z;
    const unsigned short* __restrict__ X16 = m ? X16t : X16s;
    const float* __restrict__ sq = m ? sqt : sqs;
    unsigned short* __restrict__ D = (unsigned short*)(m ? Dt : Ds);
    unsigned long long* br = best_row + m * N_NODES;
    unsigned* rt = rowtile + (size_t)m * N_NODES * 64;

    __shared__ __align__(16) unsigned short Abuf[64 * 128];
    __shared__ __align__(16) unsigned short Bbuf[64 * 128];
    __shared__ unsigned colminLDS[4 * 64];
    unsigned short* tile16 = Abuf;            // aliased after barrier (64*72*2 = 9216B)

    const int t = threadIdx.x;

    #pragma unroll
    for (int p = 0; p < 4; p++) {
        int f = t + p * 256;
        int r = f >> 4, c8 = f & 15;
        int slot = c8 ^ (r & 7);
        uint4 va = *(const uint4*)&X16[(size_t)(bi + r) * DIMS + c8 * 8];
        *(uint4*)&Abuf[r * 128 + slot * 8] = va;
        uint4 vb = *(const uint4*)&X16[(size_t)(bj + r) * DIMS + c8 * 8];
        *(uint4*)&Bbuf[r * 128 + slot * 8] = vb;
    }
    __syncthreads();

    const int wave = t >> 6, lane = t & 63;
    const int l15 = lane & 15, kg = lane >> 4;

    const int rowA = wave * 16 + l15;
    short8 afrag[4];
    #pragma unroll
    for (int s = 0; s < 4; s++) {
        int c8 = s * 4 + kg;
        int slot = c8 ^ (rowA & 7);
        afrag[s] = *(const short8*)&Abuf[rowA * 128 + slot * 8];
    }
    __syncthreads();   // all Abuf reads done before tile16 aliasing writes

    f32x4 acc[4] = {};
    #pragma unroll
    for (int n = 0; n < 4; n++) {
        const int rowB = n * 16 + l15;
        #pragma unroll
        for (int s = 0; s < 4; s++) {
            int c8 = s * 4 + kg;
            int slot = c8 ^ (rowB & 7);
            short8 bfrag = *(const short8*)&Bbuf[rowB * 128 + slot * 8];
            acc[n] = __builtin_amdgcn_mfma_f32_16x16x32_bf16(afrag[s], bfrag, acc[n], 0, 0, 0);
        }
    }

    const int r0 = wave * 16 + kg * 4;
    float sqi[4];
    #pragma unroll
    for (int rr = 0; rr < 4; rr++) sqi[rr] = sq[bi + r0 + rr];

    unsigned rowmin[4] = {U32_INF, U32_INF, U32_INF, U32_INF};   // (d16<<12)|globalcol
    unsigned colmin[4] = {U32_INF, U32_INF, U32_INF, U32_INF};   // (d16<<12)|localrow
    #pragma unroll
    for (int n = 0; n < 4; n++) {
        const int col = bj + n * 16 + l15;
        const float sqj = sq[col];
        #pragma unroll
        for (int rr = 0; rr < 4; rr++) {
            float d2 = sqi[rr] + sqj - 2.0f * acc[n][rr];
            float dd = sqrtf(fmaxf(d2, EPSF));
            unsigned hb = (unsigned)__half_as_ushort(__float2half(dd));
            tile16[(r0 + rr) * 72 + n * 16 + l15] = (unsigned short)hb;
            if ((bi + r0 + rr) != col) {
                rowmin[rr] = u32min(rowmin[rr], (hb << 12) | (unsigned)col);
                colmin[n]  = u32min(colmin[n],  (hb << 12) | (unsigned)(r0 + rr));
            }
        }
    }
    #pragma unroll
    for (int rr = 0; rr < 4; rr++) {
        unsigned k = rowmin[rr];
        #pragma unroll
        for (int s = 8; s; s >>= 1) k = u32min(k, (unsigned)__shfl_xor((int)k, s));
        if (l15 == 0) {
            const unsigned row = (unsigned)(bi + r0 + rr);
            rt[(size_t)row * 64 + (bj >> 6)] = k;            // tile lower bound
            unsigned j = k & 0xFFFu, d16 = k >> 12;
            unsigned a = row < j ? row : j, b2 = row < j ? j : row;
            atomicMin(&br[row],
                ((unsigned long long)d16 << 24) | ((unsigned long long)a << 12) | b2);
        }
    }
    #pragma unroll
    for (int n = 0; n < 4; n++) {
        unsigned k = colmin[n];
        k = u32min(k, (unsigned)__shfl_xor((int)k, 16));
        k = u32min(k, (unsigned)__shfl_xor((int)k, 32));
        if (kg == 0) colminLDS[wave * 64 + n * 16 + l15] = k;
    }
    __syncthreads();

    #pragma unroll
    for (int q = 0; q < 2; q++) {
        int lin = t * 2 + q;
        int r = lin >> 3, c8 = lin & 7;
        uint4 v = *(const uint4*)&tile16[r * 72 + c8 * 8];
        *(uint4*)&D[(size_t)(bi + r) * N_NODES + bj + c8 * 8] = v;
    }
    if (bi != bj) {
        #pragma unroll
        for (int q = 0; q < 2; q++) {
            int lin = t * 2 + q;
            int c = lin >> 3, r8 = lin & 7;
            unsigned w[4];
            #pragma unroll
            for (int h = 0; h < 4; h++) {
                unsigned lo = tile16[(r8 * 8 + h * 2) * 72 + c];
                unsigned hi = tile16[(r8 * 8 + h * 2 + 1) * 72 + c];
                w[h] = lo | (hi << 16);
            }
            uint4 v = make_uint4(w[0], w[1], w[2], w[3]);
            *(uint4*)&D[(size_t)(bj + c) * N_NODES + bi + r8 * 8] = v;
        }
        if (t < 64) {
            unsigned k = colminLDS[t];
            k = u32min(k, colminLDS[64 + t]);
            k = u32min(k, colminLDS[128 + t]);
            k = u32min(k, colminLDS[192 + t]);
            unsigned d16 = k >> 12, lrow = k & 0xFFFu;
            rt[(size_t)(bj + t) * 64 + (bi >> 6)] = (d16 << 12) | (unsigned)(bi + lrow);
            unsigned long long key64 = ((unsigned long long)d16 << 24) |
                ((unsigned long long)(bi + lrow) << 12) | (unsigned)(bj + t);
            atomicMin(&br[bj + t], key64);
        }
    }
}

// ---------------- Boruvka scan: cached edge -> tile-pruned -> linear fallback -
// grid (256, 2), block 1024 (16 independent waves; one row per wave; no LDS).
__global__ __launch_bounds__(1024) void boruvka_scan(const unsigned short* __restrict__ D0,
                                                     const unsigned short* __restrict__ D1,
                                                     const unsigned short* __restrict__ comp16,
                                                     const unsigned* __restrict__ rowtile,
                                                     unsigned long long* __restrict__ best_row,
                                                     unsigned long long* __restrict__ best_comp,
                                                     const unsigned* __restrict__ done) {
    const int m = blockIdx.y;
    if (done[m]) return;
    const unsigned short* __restrict__ D = m ? D1 : D0;
    const unsigned short* __restrict__ cm = comp16 + m * N_NODES;
    const unsigned* __restrict__ rt = rowtile + (size_t)m * N_NODES * 64;
    unsigned long long* br = best_row + m * N_NODES;
    unsigned long long* bc = best_comp + m * N_NODES;

    const int t = threadIdx.x;
    const int wave = t >> 6, lane = t & 63;
    const int r = blockIdx.x * 16 + wave;

    const unsigned short ci16 = cm[r];
    unsigned long long cached = br[r];
    bool valid;
    if (cached == KEY_INF) {
        valid = true;                          // no foreign comps remain
    } else {
        unsigned canon = (unsigned)(cached & 0xFFFFFFu);
        unsigned a = canon >> 12, b = canon & 0xFFFu;
        unsigned j = (a == (unsigned)r) ? b : a;
        valid = (cm[j] != ci16);
    }

    if (!valid) {
        const unsigned short* row = D + (size_t)r * N_NODES;
        // --- tile-pruned branch & bound ---
        unsigned tm = rt[(size_t)r * 64 + lane];   // lane <-> tile
        bool scanned = false;
        unsigned B = U32_INF;                       // best foreign (d16<<12)|col
        #pragma unroll 1
        for (int it = 0; it < DESCEND_CAP; it++) {
            unsigned long long my = ((unsigned long long)(scanned ? U32_INF : tm) << 8) | (unsigned)lane;
            #pragma unroll
            for (int s = 32; s; s >>= 1) my = u64min(my, shfl_xor_u64(my, s));
            unsigned wtm = (unsigned)(my >> 8);
            if (wtm >= B) break;                    // no tile can beat current best
            int tl = (int)(my & 0xFFu);
            int c0 = tl * 64 + lane;
            unsigned short dv = row[c0];
            unsigned short cv = cm[c0];
            unsigned cand = (cv != ci16) ? (((unsigned)dv << 12) | (unsigned)c0) : U32_INF;
            #pragma unroll
            for (int s = 32; s; s >>= 1) cand = u32min(cand, (unsigned)__shfl_xor((int)cand, s));
            B = u32min(B, cand);
            if (lane == tl) scanned = true;
        }
        // fallback needed if an unscanned tile could still beat B
        {
            unsigned myr = scanned ? U32_INF : tm;
            #pragma unroll
            for (int s = 32; s; s >>= 1) myr = u32min(myr, (unsigned)__shfl_xor((int)myr, s));
            if (myr < B) {
                // linear full-row scan (comps from global, L2-hot)
                unsigned best32 = B;
                const unsigned cirep = (unsigned)ci16 | ((unsigned)ci16 << 16);
                #pragma unroll 4
                for (int it = 0; it < 8; it++) {
                    const int e0 = it * 512 + lane * 8;
                    uint4 dvv = *(const uint4*)&row[e0];
                    uint4 cvv = *(const uint4*)&cm[e0];
                    unsigned px = cvv.x ^ cirep, py = cvv.y ^ cirep;
                    unsigned pz = cvv.z ^ cirep, pw = cvv.w ^ cirep;
                    if (px | py | pz | pw) {
                        unsigned dws[4] = {dvv.x, dvv.y, dvv.z, dvv.w};
                        unsigned pp[4] = {px, py, pz, pw};
                        #pragma unroll
                        for (int h = 0; h < 4; h++) {
                            unsigned j0 = (unsigned)(e0 + h * 2);
                            if (pp[h] & 0xFFFFu)
                                best32 = u32min(best32, ((dws[h] & 0xFFFFu) << 12) | j0);
                            if (pp[h] >> 16)
                                best32 = u32min(best32, ((dws[h] >> 16) << 12) | (j0 + 1));
                        }
                    }
                }
                #pragma unroll
                for (int s = 32; s; s >>= 1) best32 = u32min(best32, (unsigned)__shfl_xor((int)best32, s));
                B = best32;
            }
        }
        if (B != U32_INF) {
            unsigned j = B & 0xFFFu, d16 = B >> 12;
            unsigned a = (unsigned)r < j ? (unsigned)r : j;
            unsigned b2 = (unsigned)r < j ? j : (unsigned)r;
            cached = ((unsigned long long)d16 << 24) | ((unsigned long long)a << 12) | b2;
        } else {
            cached = KEY_INF;
        }
        if (lane == 0) br[r] = cached;
    }

    if (lane == 0 && cached != KEY_INF) atomicMin(&bc[ci16], cached);
}

// ---------------- Boruvka merge (separate dispatch; u16 comps) ----------------
__global__ __launch_bounds__(1024) void boruvka_merge(unsigned short* __restrict__ comp16,
                                                      unsigned long long* __restrict__ best_comp,
                                                      float* __restrict__ deaths,
                                                      unsigned* __restrict__ cnt,
                                                      unsigned* __restrict__ done) {
    const int m = blockIdx.x;
    if (done[m]) return;
    unsigned short* cm = comp16 + m * N_NODES;
    unsigned long long* bc = best_comp + m * N_NODES;
    float* dth = deaths + m * N_NODES;

    __shared__ unsigned short s_mc[N_NODES];
    __shared__ unsigned short s_mp[N_NODES];
    __shared__ unsigned long long s_bc[N_NODES];

    const int t = threadIdx.x;
    for (int i = t; i < N_NODES; i += 1024) {
        s_mc[i] = cm[i];
        s_mp[i] = (unsigned short)i;
        s_bc[i] = bc[i];
    }
    __syncthreads();

    for (int i = t; i < N_NODES; i += 1024) {
        unsigned long long k = s_bc[i];
        if (k != KEY_INF) {
            unsigned canon = (unsigned)(k & 0xFFFFFFu);
            unsigned a = canon >> 12, b = canon & 0xFFFu;
            unsigned ca = s_mc[a], cb = s_mc[b];
            unsigned other = (ca == (unsigned)i) ? cb : ca;
            s_mp[i] = (unsigned short)other;
            bool mutual = (s_bc[other] == k);
            if (!mutual || (unsigned)i < other) {
                unsigned idx = atomicAdd(&cnt[m], 1u);
                dth[idx] = half_bits_to_f32((unsigned short)(k >> 24));
            }
        }
    }
    __syncthreads();

    unsigned nv[4];
    #pragma unroll
    for (int q = 0; q < 4; q++) {
        unsigned i = (unsigned)(t + q * 1024);
        unsigned p = s_mp[i], pp = s_mp[p];
        nv[q] = (pp == i) ? (i < p ? i : p) : p;
    }
    __syncthreads();
    #pragma unroll
    for (int q = 0; q < 4; q++) s_mp[t + q * 1024] = (unsigned short)nv[q];
    __syncthreads();

    #pragma unroll
    for (int q = 0; q < 4; q++) {
        unsigned rt = (unsigned)(t + q * 1024);
        unsigned p = s_mp[rt];
        while (p != rt) { rt = p; p = s_mp[rt]; }
        nv[q] = rt;
    }
    __syncthreads();
    #pragma unroll
    for (int q = 0; q < 4; q++) s_mp[t + q * 1024] = (unsigned short)nv[q];
    __syncthreads();

    for (int i = t; i < N_NODES; i += 1024) {
        cm[i] = s_mp[s_mc[i]];
        bc[i] = KEY_INF;
    }
    __syncthreads();
    if (t == 0) {
        unsigned c = atomicAdd(&cnt[m], 0u);
        if (c >= N_NODES - 1) done[m] = 1u;
    }
}

// ---------------- sort (hybrid bitonic: shuffles for j<=32) ----------------
__global__ __launch_bounds__(1024) void sort_kernel(float* __restrict__ deaths) {
    float* d = deaths + blockIdx.x * N_NODES;
    __shared__ float s[N_NODES];
    const int t = threadIdx.x;
    for (int i = t; i < N_NODES - 1; i += 1024) s[i] = d[i];
    if (t == 0) s[N_NODES - 1] = BIGF;
    __syncthreads();

    {
        float v[4];
        #pragma unroll
        for (int q = 0; q < 4; q++) v[q] = s[t + q * 1024];
        #pragma unroll
        for (int k = 2; k <= 32; k <<= 1) {
            for (int j = k >> 1; j; j >>= 1) {
                #pragma unroll
                for (int q = 0; q < 4; q++) {
                    float o = __shfl_xor(v[q], j);
                    bool up  = (t & j) == 0;
                    bool asc = (((t + q * 1024) & k) == 0);
                    float lo = fminf(v[q], o), hi = fmaxf(v[q], o);
                    v[q] = (asc == up) ? lo : hi;
                }
            }
        }
        #pragma unroll
        for (int q = 0; q < 4; q++) s[t + q * 1024] = v[q];
    }
    __syncthreads();

    for (int k = 64; k <= N_NODES; k <<= 1) {
        for (int j = k >> 1; j >= 64; j >>= 1) {
            #pragma unroll
            for (int q = 0; q < 4; q++) {
                int i = t + q * 1024;
                int p = i ^ j;
                if (p > i) {
                    float a = s[i], b = s[p];
                    bool asc = (i & k) == 0;
                    if ((a > b) == asc) { s[i] = b; s[p] = a; }
                }
            }
            __syncthreads();
        }
        float v[4];
        #pragma unroll
        for (int q = 0; q < 4; q++) v[q] = s[t + q * 1024];
        for (int j = 32; j; j >>= 1) {
            #pragma unroll
            for (int q = 0; q < 4; q++) {
                float o = __shfl_xor(v[q], j);
                bool up  = (t & j) == 0;
                bool asc = (((t + q * 1024) & k) == 0);
                float lo = fminf(v[q], o), hi = fmaxf(v[q], o);
                v[q] = (asc == up) ? lo : hi;
            }
        }
        #pragma unroll
        for (int q = 0; q < 4; q++) s[t + q * 1024] = v[q];
        __syncthreads();
    }
    for (int i = t; i < N_NODES - 1; i += 1024) d[i] = s[i];
}

// ---------------- finalize ----------------
__global__ __launch_bounds__(256) void finalize_kernel(const float* __restrict__ deaths,
                                                       const float* __restrict__ partials,
                                                       int n_partials,
                                                       float* __restrict__ out) {
    const float* ds = deaths;
    const float* dt = deaths + N_NODES;
    float a = 0.f;
    for (int i = threadIdx.x; i < N_NODES - 1; i += 256) {
        float d = ds[i] - dt[i];
        a += d * d;
    }
    float topo_sum = block_reduce_sum_256(a);
    float r = 0.f;
    for (int i = threadIdx.x; i < n_partials; i += 256) r += partials[i];
    float repr_sum = block_reduce_sum_256(r);
    if (threadIdx.x == 0) {
        float repr = repr_sum / (float)(N_NODES * DIMS);
        float topo = topo_sum / (float)(2 * (N_NODES - 1));
        out[0] = 0.5f * repr + 0.5f * topo;
        out[1] = repr;
        out[2] = topo;
    }
}

// ---------------- host ----------------

extern "C" void kernel_launch(void* const* d_in, const int* in_sizes, int n_in,
                              void* d_out, int out_size, void* d_ws, size_t ws_size,
                              hipStream_t stream) {
    const float* S = (const float*)d_in[0];
    const float* T = (const float*)d_in[1];
    float* out = (float*)d_out;

    const size_t nn = (size_t)N_NODES * N_NODES;
    char* p = (char*)d_ws;
    __half* Ds = (__half*)p;                   p += nn * 2;
    __half* Dt = (__half*)p;                   p += nn * 2;
    unsigned short* X16s = (unsigned short*)p; p += (size_t)N_NODES * DIMS * 2;
    unsigned short* X16t = (unsigned short*)p; p += (size_t)N_NODES * DIMS * 2;
    unsigned long long* best_comp = (unsigned long long*)p; p += 2 * N_NODES * 8;
    unsigned long long* best_row  = (unsigned long long*)p; p += 2 * N_NODES * 8;
    unsigned* rowtile  = (unsigned*)p; p += (size_t)2 * N_NODES * 64 * 4;
    float*    sqs      = (float*)p;    p += N_NODES * 4;
    float*    sqt      = (float*)p;    p += N_NODES * 4;
    float*    deaths   = (float*)p;    p += 2 * N_NODES * 4;
    float*    partials = (float*)p;    p += 512 * 4;
    unsigned short* comp16 = (unsigned short*)p; p += 2 * N_NODES * 2;
    unsigned* cnt      = (unsigned*)p; p += 2 * 4;
    unsigned* done     = (unsigned*)p;

    prep_kernel<<<N_NODES / 8, 256, 0, stream>>>(S, T, X16s, X16t, sqs, sqt, partials,
                                                 comp16, best_comp, best_row, cnt, done);

    dim3 dg(N_NODES / 64, N_NODES / 64, 2);
    dist_kernel<<<dg, 256, 0, stream>>>(X16s, X16t, sqs, sqt, Ds, Dt, best_row, rowtile);

    dim3 sg(N_NODES / 16, 2);
    for (int r = 0; r < 12; r++) {
        boruvka_scan<<<sg, 1024, 0, stream>>>((const unsigned short*)Ds,
                                              (const unsigned short*)Dt,
                                              comp16, rowtile, best_row, best_comp, done);
        boruvka_merge<<<2, 1024, 0, stream>>>(comp16, best_comp, deaths, cnt, done);
    }
    sort_kernel<<<2, 1024, 0, stream>>>(deaths);
    finalize_kernel<<<1, 256, 0, stream>>>(deaths, partials, 512, out);
}